// Round 3
// baseline (642.646 us; speedup 1.0000x reference)
//
#include <hip/hip_runtime.h>
#include <hip/hip_bf16.h>

#define N_NODES 50000
#define E_EDGES 800000
#define NH 4
#define NEG_SLOPE 0.2f
#define LN_EPS 1e-5f

// ---------------------------------------------------------------------------
// CSR row_ptr from sorted dst via per-node lower_bound (no atomics).
// rp[d] = first edge index with dst[e] >= d;  segment(d) = [rp[d], rp[d+1])
// ---------------------------------------------------------------------------
__global__ void k_rowptr(const int* __restrict__ dst, int* __restrict__ rp) {
    int d = blockIdx.x * blockDim.x + threadIdx.x;
    if (d > N_NODES) return;
    int lo = 0, hi = E_EDGES;
    while (lo < hi) {
        int mid = (lo + hi) >> 1;
        if (dst[mid] < d) lo = mid + 1; else hi = mid;
    }
    rp[d] = lo;
}

// ---------------------------------------------------------------------------
// Node GEMM: fs[N,256] = h @ W, el/er[N,4] = head-dot(fs, al/ar),
// resid[N,64] = h @ resw + resb.  8 nodes per 256-thread block.
// Thread t owns output column t; wave id == head id for el/er reduction.
// ---------------------------------------------------------------------------
template<int K>
__global__ __launch_bounds__(256) void k_gemm(
    const float* __restrict__ hin, const float* __restrict__ W,
    const float* __restrict__ al, const float* __restrict__ ar,
    const float* __restrict__ resw, const float* __restrict__ resb,
    float* __restrict__ fs, float* __restrict__ el, float* __restrict__ er,
    float* __restrict__ resid)
{
    __shared__ __align__(16) float hl[K * 8];   // [k][node] layout
    const int n0 = blockIdx.x * 8;
    const int t  = threadIdx.x;

    for (int idx = t; idx < 8 * K; idx += 256) {
        int n = idx / K, k = idx - n * K;
        int node = n0 + n;
        hl[k * 8 + n] = (node < N_NODES) ? hin[(long long)node * K + k] : 0.f;
    }
    __syncthreads();

    float acc[8] = {0.f,0.f,0.f,0.f,0.f,0.f,0.f,0.f};
    #pragma unroll 4
    for (int k = 0; k < K; ++k) {
        float w = W[k * 256 + t];
        const float4 a0 = *(const float4*)&hl[k * 8];
        const float4 a1 = *(const float4*)&hl[k * 8 + 4];
        acc[0] = fmaf(a0.x, w, acc[0]);
        acc[1] = fmaf(a0.y, w, acc[1]);
        acc[2] = fmaf(a0.z, w, acc[2]);
        acc[3] = fmaf(a0.w, w, acc[3]);
        acc[4] = fmaf(a1.x, w, acc[4]);
        acc[5] = fmaf(a1.y, w, acc[5]);
        acc[6] = fmaf(a1.z, w, acc[6]);
        acc[7] = fmaf(a1.w, w, acc[7]);
    }

    const int h = t >> 6, lane = t & 63;

    #pragma unroll
    for (int n = 0; n < 8; ++n) {
        int node = n0 + n;
        if (node < N_NODES) fs[(long long)node * 256 + t] = acc[n];
    }

    // el/er: wave h reduces over its 64 lanes (columns h*64..h*64+63)
    float alc = al[t], arc = ar[t];
    float e_l[8], e_r[8];
    #pragma unroll
    for (int n = 0; n < 8; ++n) { e_l[n] = acc[n] * alc; e_r[n] = acc[n] * arc; }
    #pragma unroll
    for (int o = 32; o > 0; o >>= 1) {
        #pragma unroll
        for (int n = 0; n < 8; ++n) {
            e_l[n] += __shfl_xor(e_l[n], o, 64);
            e_r[n] += __shfl_xor(e_r[n], o, 64);
        }
    }
    if (lane == 0) {
        #pragma unroll
        for (int n = 0; n < 8; ++n) {
            int node = n0 + n;
            if (node < N_NODES) {
                el[node * NH + h] = e_l[n];
                er[node * NH + h] = e_r[n];
            }
        }
    }

    // resid: thread (h, lane) -> c0 = lane, nodes {h, h+4}
    const int c0 = lane;
    float r0 = 0.f, r1 = 0.f;
    for (int k = 0; k < K; ++k) {
        float w = resw[k * 64 + c0];
        r0 = fmaf(hl[k * 8 + h],     w, r0);
        r1 = fmaf(hl[k * 8 + h + 4], w, r1);
    }
    float bb = resb[c0];
    if (n0 + h     < N_NODES) resid[(long long)(n0 + h)     * 64 + c0] = r0 + bb;
    if (n0 + h + 4 < N_NODES) resid[(long long)(n0 + h + 4) * 64 + c0] = r1 + bb;
}

// ---------------------------------------------------------------------------
// Per-destination-node edge softmax + aggregation + head-mean + residual +
// LayerNorm + ReLU (+ fused prediction head when FINAL).
// Block = 256 threads = one node; wave w handles head w for softmax stats.
// ---------------------------------------------------------------------------
template<bool FINAL>
__global__ __launch_bounds__(256) void k_agg(
    const int* __restrict__ rp, const int* __restrict__ src,
    const float* __restrict__ fs, const float* __restrict__ el,
    const float* __restrict__ er, const float* __restrict__ resid,
    const float* __restrict__ g, const float* __restrict__ b,
    const float* __restrict__ predw, const float* __restrict__ predb,
    float* __restrict__ out)
{
    __shared__ float alds[NH * 64];
    __shared__ int   slds[64];
    __shared__ float ms[NH], rs[NH];
    __shared__ float flds[256];
    __shared__ float hl2[64];

    const int d    = blockIdx.x;
    const int t    = threadIdx.x;
    const int h    = t >> 6;
    const int lane = t & 63;
    const int start = rp[d], end = rp[d + 1];

    const float erd = er[d * NH + h];

    if (end > start) {
        // phase 1: per-head max over incoming edges
        float m = -3.0e38f;
        for (int j = start + lane; j < end; j += 64) {
            float e = el[src[j] * NH + h] + erd;
            e = e > 0.f ? e : NEG_SLOPE * e;
            m = fmaxf(m, e);
        }
        #pragma unroll
        for (int o = 32; o > 0; o >>= 1) m = fmaxf(m, __shfl_xor(m, o, 64));
        // phase 2: sum of exp
        float s = 0.f;
        for (int j = start + lane; j < end; j += 64) {
            float e = el[src[j] * NH + h] + erd;
            e = e > 0.f ? e : NEG_SLOPE * e;
            s += __expf(e - m);
        }
        #pragma unroll
        for (int o = 32; o > 0; o >>= 1) s += __shfl_xor(s, o, 64);
        if (lane == 0) { ms[h] = m; rs[h] = 1.f / s; }
    }
    __syncthreads();

    // phase 3: weighted gather of fs[src], chunks of 64 edges staged in LDS
    float acc = 0.f;
    for (int cs = start; cs < end; cs += 64) {
        int cnt = min(64, end - cs);
        if (lane < cnt) {
            int j  = cs + lane;
            int sj = src[j];
            if (h == 0) slds[lane] = sj;
            float e = el[sj * NH + h] + erd;
            e = e > 0.f ? e : NEG_SLOPE * e;
            alds[h * 64 + lane] = __expf(e - ms[h]) * rs[h];
        }
        __syncthreads();
        for (int jj = 0; jj < cnt; ++jj) {
            acc += alds[h * 64 + jj] * fs[(long long)slds[jj] * 256 + t];
        }
        __syncthreads();
    }

    // epilogue: head-mean + residual + LN + ReLU (wave 0 only)
    flds[t] = acc;
    __syncthreads();
    if (t < 64) {
        float v = 0.25f * (flds[t] + flds[t + 64] + flds[t + 128] + flds[t + 192])
                + resid[d * 64 + t];
        float s1 = v, s2 = v * v;
        #pragma unroll
        for (int o = 32; o > 0; o >>= 1) {
            s1 += __shfl_xor(s1, o, 64);
            s2 += __shfl_xor(s2, o, 64);
        }
        float mu  = s1 * (1.f / 64.f);
        float var = s2 * (1.f / 64.f) - mu * mu;
        float inv = 1.f / sqrtf(fmaxf(var, 0.f) + LN_EPS);
        float y = (v - mu) * inv * g[t] + b[t];
        y = fmaxf(y, 0.f);
        if (FINAL) hl2[t] = y;
        else       out[d * 64 + t] = y;
    }
    if (FINAL) {
        __syncthreads();
        if (t < 64) {
            float o = predb[t];
            for (int k = 0; k < 64; ++k) o = fmaf(hl2[k], predw[k * 64 + t], o);
            out[d * 64 + t] = o;
        }
    }
}

// ---------------------------------------------------------------------------
extern "C" void kernel_launch(void* const* d_in, const int* in_sizes, int n_in,
                              void* d_out, int out_size, void* d_ws, size_t ws_size,
                              hipStream_t stream)
{
    const float* feats = (const float*)d_in[0];
    const int*   src   = (const int*)  d_in[1];
    const int*   dst   = (const int*)  d_in[2];
    const float* W0    = (const float*)d_in[3];
    const float* al0   = (const float*)d_in[4];
    const float* ar0   = (const float*)d_in[5];
    const float* resw0 = (const float*)d_in[6];
    const float* resb0 = (const float*)d_in[7];
    const float* g0    = (const float*)d_in[8];
    const float* b0    = (const float*)d_in[9];
    const float* W1    = (const float*)d_in[10];
    const float* al1   = (const float*)d_in[11];
    const float* ar1   = (const float*)d_in[12];
    const float* resw1 = (const float*)d_in[13];
    const float* resb1 = (const float*)d_in[14];
    const float* g1    = (const float*)d_in[15];
    const float* b1    = (const float*)d_in[16];
    const float* predw = (const float*)d_in[17];
    const float* predb = (const float*)d_in[18];
    float* out = (float*)d_out;

    char* ws = (char*)d_ws;
    int*   rp    = (int*)ws;                               // (N+1) ints
    float* fs    = (float*)(ws + 200192);                  // N*256 f32
    float* el    = fs + (size_t)N_NODES * 256;             // N*4
    float* er    = el + (size_t)N_NODES * 4;               // N*4
    float* resid = er + (size_t)N_NODES * 4;               // N*64
    float* h1    = resid + (size_t)N_NODES * 64;           // N*64

    k_rowptr<<<(N_NODES + 1 + 255) / 256, 256, 0, stream>>>(dst, rp);

    k_gemm<128><<<(N_NODES + 7) / 8, 256, 0, stream>>>(
        feats, W0, al0, ar0, resw0, resb0, fs, el, er, resid);
    k_agg<false><<<N_NODES, 256, 0, stream>>>(
        rp, src, fs, el, er, resid, g0, b0, nullptr, nullptr, h1);

    k_gemm<64><<<(N_NODES + 7) / 8, 256, 0, stream>>>(
        h1, W1, al1, ar1, resw1, resb1, fs, el, er, resid);
    k_agg<true><<<N_NODES, 256, 0, stream>>>(
        rp, src, fs, el, er, resid, g1, b1, predw, predb, out);
}

// Round 4
// 584.084 us; speedup vs baseline: 1.1003x; 1.1003x over previous
//
#include <hip/hip_runtime.h>
#include <hip/hip_bf16.h>

#define N_NODES 50000
#define E_EDGES 800000
#define NH 4
#define NEG_SLOPE 0.2f
#define LN_EPS 1e-5f

// ---------------------------------------------------------------------------
// CSR row_ptr from sorted dst via per-node lower_bound (no atomics).
// ---------------------------------------------------------------------------
__global__ void k_rowptr(const int* __restrict__ dst, int* __restrict__ rp) {
    int d = blockIdx.x * blockDim.x + threadIdx.x;
    if (d > N_NODES) return;
    int lo = 0, hi = E_EDGES;
    while (lo < hi) {
        int mid = (lo + hi) >> 1;
        if (dst[mid] < d) lo = mid + 1; else hi = mid;
    }
    rp[d] = lo;
}

// ---------------------------------------------------------------------------
// Node GEMM: fs[N,256] = h @ W  (stored bf16), el/er[N,4] (fp32, from fp32
// accumulators), resid[N,64] = h @ resw + resb.  8 nodes / 256-thread block.
// ---------------------------------------------------------------------------
template<int K>
__global__ __launch_bounds__(256) void k_gemm(
    const float* __restrict__ hin, const float* __restrict__ W,
    const float* __restrict__ al, const float* __restrict__ ar,
    const float* __restrict__ resw, const float* __restrict__ resb,
    __hip_bfloat16* __restrict__ fs, float* __restrict__ el,
    float* __restrict__ er, float* __restrict__ resid)
{
    __shared__ __align__(16) float hl[K * 8];   // [k][node] layout
    const int n0 = blockIdx.x * 8;
    const int t  = threadIdx.x;

    for (int idx = t; idx < 8 * K; idx += 256) {
        int n = idx / K, k = idx - n * K;
        int node = n0 + n;
        hl[k * 8 + n] = (node < N_NODES) ? hin[(long long)node * K + k] : 0.f;
    }
    __syncthreads();

    float acc[8] = {0.f,0.f,0.f,0.f,0.f,0.f,0.f,0.f};
    #pragma unroll 4
    for (int k = 0; k < K; ++k) {
        float w = W[k * 256 + t];
        const float4 a0 = *(const float4*)&hl[k * 8];
        const float4 a1 = *(const float4*)&hl[k * 8 + 4];
        acc[0] = fmaf(a0.x, w, acc[0]);
        acc[1] = fmaf(a0.y, w, acc[1]);
        acc[2] = fmaf(a0.z, w, acc[2]);
        acc[3] = fmaf(a0.w, w, acc[3]);
        acc[4] = fmaf(a1.x, w, acc[4]);
        acc[5] = fmaf(a1.y, w, acc[5]);
        acc[6] = fmaf(a1.z, w, acc[6]);
        acc[7] = fmaf(a1.w, w, acc[7]);
    }

    const int h = t >> 6, lane = t & 63;

    #pragma unroll
    for (int n = 0; n < 8; ++n) {
        int node = n0 + n;
        if (node < N_NODES) fs[(long long)node * 256 + t] = __float2bfloat16(acc[n]);
    }

    // el/er from fp32 accumulators: wave h reduces its 64 lanes
    float alc = al[t], arc = ar[t];
    float e_l[8], e_r[8];
    #pragma unroll
    for (int n = 0; n < 8; ++n) { e_l[n] = acc[n] * alc; e_r[n] = acc[n] * arc; }
    #pragma unroll
    for (int o = 32; o > 0; o >>= 1) {
        #pragma unroll
        for (int n = 0; n < 8; ++n) {
            e_l[n] += __shfl_xor(e_l[n], o, 64);
            e_r[n] += __shfl_xor(e_r[n], o, 64);
        }
    }
    if (lane == 0) {
        #pragma unroll
        for (int n = 0; n < 8; ++n) {
            int node = n0 + n;
            if (node < N_NODES) {
                el[node * NH + h] = e_l[n];
                er[node * NH + h] = e_r[n];
            }
        }
    }

    // resid: thread (h, lane) -> col = lane, nodes {h, h+4}
    const int c0 = lane;
    float r0 = 0.f, r1 = 0.f;
    for (int k = 0; k < K; ++k) {
        float w = resw[k * 64 + c0];
        r0 = fmaf(hl[k * 8 + h],     w, r0);
        r1 = fmaf(hl[k * 8 + h + 4], w, r1);
    }
    float bb = resb[c0];
    if (n0 + h     < N_NODES) resid[(long long)(n0 + h)     * 64 + c0] = r0 + bb;
    if (n0 + h + 4 < N_NODES) resid[(long long)(n0 + h + 4) * 64 + c0] = r1 + bb;
}

// ---------------------------------------------------------------------------
// Per-destination-node edge softmax + aggregation (bf16 gather, 2 edges per
// iteration) + head-mean + residual + LN + ReLU (+ pred head when FINAL).
// ---------------------------------------------------------------------------
template<bool FINAL>
__global__ __launch_bounds__(256) void k_agg(
    const int* __restrict__ rp, const int* __restrict__ src,
    const unsigned int* __restrict__ fs_u,   // [N][128] uints = 256 bf16
    const float* __restrict__ el, const float* __restrict__ er,
    const float* __restrict__ resid,
    const float* __restrict__ g, const float* __restrict__ b,
    const float* __restrict__ predw, const float* __restrict__ predb,
    float* __restrict__ out)
{
    __shared__ float alds[NH * 64];
    __shared__ int   slds[64];
    __shared__ float ms[NH], rs[NH];
    __shared__ float flds2[2][256];
    __shared__ float hl2[64];

    const int d    = blockIdx.x;
    const int t    = threadIdx.x;
    const int h    = t >> 6;       // head for softmax staging (wave id)
    const int lane = t & 63;
    const int p    = t >> 7;       // edge parity group (0/1)
    const int q    = t & 127;      // uint column index -> cols 2q, 2q+1
    const int hh   = q >> 5;       // head of both owned columns
    const int start = rp[d], end = rp[d + 1];

    const float erd = er[d * NH + h];

    if (end > start) {
        // phase 1: per-head max over incoming edges
        float m = -3.0e38f;
        for (int j = start + lane; j < end; j += 64) {
            float e = el[src[j] * NH + h] + erd;
            e = e > 0.f ? e : NEG_SLOPE * e;
            m = fmaxf(m, e);
        }
        #pragma unroll
        for (int o = 32; o > 0; o >>= 1) m = fmaxf(m, __shfl_xor(m, o, 64));
        // phase 2: sum of exp
        float s = 0.f;
        for (int j = start + lane; j < end; j += 64) {
            float e = el[src[j] * NH + h] + erd;
            e = e > 0.f ? e : NEG_SLOPE * e;
            s += __expf(e - m);
        }
        #pragma unroll
        for (int o = 32; o > 0; o >>= 1) s += __shfl_xor(s, o, 64);
        if (lane == 0) { ms[h] = m; rs[h] = 1.f / s; }
    }
    __syncthreads();

    // phase 3: weighted gather of bf16 fs[src], 64-edge chunks, 2 edges/iter
    float accx = 0.f, accy = 0.f;
    for (int cs = start; cs < end; cs += 64) {
        int cnt = min(64, end - cs);
        {
            int   sj = 0;
            float a  = 0.f;
            if (lane < cnt) {
                sj = src[cs + lane];
                float e = el[sj * NH + h] + erd;
                e = e > 0.f ? e : NEG_SLOPE * e;
                a = __expf(e - ms[h]) * rs[h];
            }
            if (h == 0) slds[lane] = sj;      // zero-padded beyond cnt
            alds[h * 64 + lane] = a;          // zero weight beyond cnt
        }
        __syncthreads();
        #pragma unroll 4
        for (int jj = 0; jj < cnt; jj += 2) {
            int j = jj + p;                    // may be == cnt (padded, w=0)
            float w = alds[hh * 64 + j];
            unsigned int u = fs_u[(long long)slds[j] * 128 + q];
            accx = fmaf(w, __uint_as_float(u << 16), accx);
            accy = fmaf(w, __uint_as_float(u & 0xffff0000u), accy);
        }
        __syncthreads();
    }

    // combine the two parity groups + head-mean + residual + LN + ReLU
    flds2[p][2 * q]     = accx;
    flds2[p][2 * q + 1] = accy;
    __syncthreads();
    if (t < 64) {
        float v = 0.f;
        #pragma unroll
        for (int hd = 0; hd < NH; ++hd)
            v += flds2[0][hd * 64 + t] + flds2[1][hd * 64 + t];
        v = 0.25f * v + resid[d * 64 + t];
        float s1 = v, s2 = v * v;
        #pragma unroll
        for (int o = 32; o > 0; o >>= 1) {
            s1 += __shfl_xor(s1, o, 64);
            s2 += __shfl_xor(s2, o, 64);
        }
        float mu  = s1 * (1.f / 64.f);
        float var = s2 * (1.f / 64.f) - mu * mu;
        float inv = 1.f / sqrtf(fmaxf(var, 0.f) + LN_EPS);
        float y = (v - mu) * inv * g[t] + b[t];
        y = fmaxf(y, 0.f);
        if (FINAL) hl2[t] = y;
        else       out[d * 64 + t] = y;
    }
    if (FINAL) {
        __syncthreads();
        if (t < 64) {
            float o = predb[t];
            for (int k = 0; k < 64; ++k) o = fmaf(hl2[k], predw[k * 64 + t], o);
            out[d * 64 + t] = o;
        }
    }
}

// ---------------------------------------------------------------------------
extern "C" void kernel_launch(void* const* d_in, const int* in_sizes, int n_in,
                              void* d_out, int out_size, void* d_ws, size_t ws_size,
                              hipStream_t stream)
{
    const float* feats = (const float*)d_in[0];
    const int*   src   = (const int*)  d_in[1];
    const int*   dst   = (const int*)  d_in[2];
    const float* W0    = (const float*)d_in[3];
    const float* al0   = (const float*)d_in[4];
    const float* ar0   = (const float*)d_in[5];
    const float* resw0 = (const float*)d_in[6];
    const float* resb0 = (const float*)d_in[7];
    const float* g0    = (const float*)d_in[8];
    const float* b0    = (const float*)d_in[9];
    const float* W1    = (const float*)d_in[10];
    const float* al1   = (const float*)d_in[11];
    const float* ar1   = (const float*)d_in[12];
    const float* resw1 = (const float*)d_in[13];
    const float* resb1 = (const float*)d_in[14];
    const float* g1    = (const float*)d_in[15];
    const float* b1    = (const float*)d_in[16];
    const float* predw = (const float*)d_in[17];
    const float* predb = (const float*)d_in[18];
    float* out = (float*)d_out;

    char* ws = (char*)d_ws;
    int*   rp = (int*)ws;                                   // (N+1) ints
    __hip_bfloat16* fs = (__hip_bfloat16*)(ws + 200192);    // N*256 bf16
    float* el    = (float*)((char*)fs + (size_t)N_NODES * 256 * 2);
    float* er    = el + (size_t)N_NODES * 4;
    float* resid = er + (size_t)N_NODES * 4;
    float* h1    = resid + (size_t)N_NODES * 64;

    k_rowptr<<<(N_NODES + 1 + 255) / 256, 256, 0, stream>>>(dst, rp);

    k_gemm<128><<<(N_NODES + 7) / 8, 256, 0, stream>>>(
        feats, W0, al0, ar0, resw0, resb0, fs, el, er, resid);
    k_agg<false><<<N_NODES, 256, 0, stream>>>(
        rp, src, (const unsigned int*)fs, el, er, resid, g0, b0,
        nullptr, nullptr, h1);

    k_gemm<64><<<(N_NODES + 7) / 8, 256, 0, stream>>>(
        h1, W1, al1, ar1, resw1, resb1, fs, el, er, resid);
    k_agg<true><<<N_NODES, 256, 0, stream>>>(
        rp, src, (const unsigned int*)fs, el, er, resid, g1, b1,
        predw, predb, out);
}

// Round 5
// 568.738 us; speedup vs baseline: 1.1300x; 1.0270x over previous
//
#include <hip/hip_runtime.h>
#include <hip/hip_bf16.h>

#define N_NODES 50000
#define E_EDGES 800000
#define NH 4
#define NEG_SLOPE 0.2f
#define LN_EPS 1e-5f

// ---------------------------------------------------------------------------
// CSR row_ptr from sorted dst via per-node lower_bound (no atomics).
// ---------------------------------------------------------------------------
__global__ void k_rowptr(const int* __restrict__ dst, int* __restrict__ rp) {
    int d = blockIdx.x * blockDim.x + threadIdx.x;
    if (d > N_NODES) return;
    int lo = 0, hi = E_EDGES;
    while (lo < hi) {
        int mid = (lo + hi) >> 1;
        if (dst[mid] < d) lo = mid + 1; else hi = mid;
    }
    rp[d] = lo;
}

// ---------------------------------------------------------------------------
// Node GEMM: fs[N,256] = h @ W (stored bf16), el/er[N,4] fp32,
// resid[N,64] = h @ resw + resb.  16 nodes / 256-thread block.
// Thread t owns output column t across all 16 nodes (16 FMA per W element).
// ---------------------------------------------------------------------------
template<int K>
__global__ __launch_bounds__(256) void k_gemm(
    const float* __restrict__ hin, const float* __restrict__ W,
    const float* __restrict__ al, const float* __restrict__ ar,
    const float* __restrict__ resw, const float* __restrict__ resb,
    __hip_bfloat16* __restrict__ fs, float* __restrict__ el,
    float* __restrict__ er, float* __restrict__ resid)
{
    __shared__ __align__(16) float hl[K * 16];   // [k][node] layout
    const int n0 = blockIdx.x * 16;
    const int t  = threadIdx.x;

    for (int idx = t; idx < 16 * K; idx += 256) {
        int n = idx / K, k = idx - n * K;
        hl[k * 16 + n] = hin[(long long)(n0 + n) * K + k];   // 50000 % 16 == 0
    }
    __syncthreads();

    float acc[16];
    #pragma unroll
    for (int n = 0; n < 16; ++n) acc[n] = 0.f;

    #pragma unroll 2
    for (int k = 0; k < K; ++k) {
        float w = W[k * 256 + t];
        #pragma unroll
        for (int c = 0; c < 4; ++c) {
            const float4 a = *(const float4*)&hl[k * 16 + 4 * c];
            acc[4*c+0] = fmaf(a.x, w, acc[4*c+0]);
            acc[4*c+1] = fmaf(a.y, w, acc[4*c+1]);
            acc[4*c+2] = fmaf(a.z, w, acc[4*c+2]);
            acc[4*c+3] = fmaf(a.w, w, acc[4*c+3]);
        }
    }

    const int h = t >> 6, lane = t & 63;

    #pragma unroll
    for (int n = 0; n < 16; ++n)
        fs[(long long)(n0 + n) * 256 + t] = __float2bfloat16(acc[n]);

    // el/er from fp32 accumulators: wave h reduces its 64 lanes
    float alc = al[t], arc = ar[t];
    float e_l[16], e_r[16];
    #pragma unroll
    for (int n = 0; n < 16; ++n) { e_l[n] = acc[n] * alc; e_r[n] = acc[n] * arc; }
    #pragma unroll
    for (int o = 32; o > 0; o >>= 1) {
        #pragma unroll
        for (int n = 0; n < 16; ++n) {
            e_l[n] += __shfl_xor(e_l[n], o, 64);
            e_r[n] += __shfl_xor(e_r[n], o, 64);
        }
    }
    if (lane == 0) {
        #pragma unroll
        for (int n = 0; n < 16; ++n) {
            el[(n0 + n) * NH + h] = e_l[n];
            er[(n0 + n) * NH + h] = e_r[n];
        }
    }

    // resid: thread (h, lane) -> col = lane, nodes {h, h+4, h+8, h+12}
    float r[4] = {0.f, 0.f, 0.f, 0.f};
    for (int k = 0; k < K; ++k) {
        float w = resw[k * 64 + lane];
        #pragma unroll
        for (int j = 0; j < 4; ++j)
            r[j] = fmaf(hl[k * 16 + h + 4 * j], w, r[j]);
    }
    float bb = resb[lane];
    #pragma unroll
    for (int j = 0; j < 4; ++j)
        resid[(long long)(n0 + h + 4 * j) * 64 + lane] = r[j] + bb;
}

// ---------------------------------------------------------------------------
// Per-destination-node edge softmax + aggregation + head-mean + residual +
// LN + ReLU (+ pred head when FINAL).
// Gather: 8 groups of 32 lanes; group gp loads edge jj+gp's full 512B row
// as uint4 (16B/lane, cols 8l..8l+7).  Partials combined via LDS.
// ---------------------------------------------------------------------------
template<bool FINAL>
__global__ __launch_bounds__(256) void k_agg(
    const int* __restrict__ rp, const int* __restrict__ src,
    const unsigned int* __restrict__ fs_u,   // [N][128] uints = 256 bf16
    const float* __restrict__ el, const float* __restrict__ er,
    const float* __restrict__ resid,
    const float* __restrict__ g, const float* __restrict__ b,
    const float* __restrict__ predw, const float* __restrict__ predb,
    float* __restrict__ out)
{
    __shared__ float alds[NH * 64];
    __shared__ int   slds[64];
    __shared__ float ms[NH], rs[NH];
    __shared__ float flds[8][256];
    __shared__ float hl2[64];

    const int d    = blockIdx.x;
    const int t    = threadIdx.x;
    const int h    = t >> 6;       // wave id == head for softmax staging
    const int lane = t & 63;
    const int gp   = t >> 5;       // edge group (0..7)
    const int l    = t & 31;       // lane in group: owns cols 8l..8l+7
    const int hh   = l >> 3;       // head of owned cols
    const int start = rp[d], end = rp[d + 1];

    const float erd = er[d * NH + h];

    if (end > start) {
        // phase 1: per-head max over incoming edges
        float m = -3.0e38f;
        for (int j = start + lane; j < end; j += 64) {
            float e = el[src[j] * NH + h] + erd;
            e = e > 0.f ? e : NEG_SLOPE * e;
            m = fmaxf(m, e);
        }
        #pragma unroll
        for (int o = 32; o > 0; o >>= 1) m = fmaxf(m, __shfl_xor(m, o, 64));
        // phase 2: sum of exp
        float s = 0.f;
        for (int j = start + lane; j < end; j += 64) {
            float e = el[src[j] * NH + h] + erd;
            e = e > 0.f ? e : NEG_SLOPE * e;
            s += __expf(e - m);
        }
        #pragma unroll
        for (int o = 32; o > 0; o >>= 1) s += __shfl_xor(s, o, 64);
        if (lane == 0) { ms[h] = m; rs[h] = 1.f / s; }
    }
    __syncthreads();

    // phase 3: weighted gather, 64-edge chunks, 8 edges in flight
    float acc[8];
    #pragma unroll
    for (int i = 0; i < 8; ++i) acc[i] = 0.f;

    for (int cs = start; cs < end; cs += 64) {
        int cnt = min(64, end - cs);
        {
            int   sj = 0;
            float a  = 0.f;
            if (lane < cnt) {
                sj = src[cs + lane];
                float e = el[sj * NH + h] + erd;
                e = e > 0.f ? e : NEG_SLOPE * e;
                a = __expf(e - ms[h]) * rs[h];
            }
            if (h == 0) slds[lane] = sj;      // zero-padded beyond cnt
            alds[h * 64 + lane] = a;          // zero weight beyond cnt
        }
        __syncthreads();
        #pragma unroll 2
        for (int jj = 0; jj < cnt; jj += 8) {
            int j  = jj + gp;
            int jc = (j < cnt) ? j : 0;                 // clamped (w=0 if pad,
            float w = (j < cnt) ? alds[hh * 64 + j] : 0.f;  // unless cnt==64)
            const uint4 u = *((const uint4*)(fs_u + (size_t)slds[jc] * 128) + l);
            acc[0] = fmaf(w, __uint_as_float(u.x << 16),         acc[0]);
            acc[1] = fmaf(w, __uint_as_float(u.x & 0xffff0000u), acc[1]);
            acc[2] = fmaf(w, __uint_as_float(u.y << 16),         acc[2]);
            acc[3] = fmaf(w, __uint_as_float(u.y & 0xffff0000u), acc[3]);
            acc[4] = fmaf(w, __uint_as_float(u.z << 16),         acc[4]);
            acc[5] = fmaf(w, __uint_as_float(u.z & 0xffff0000u), acc[5]);
            acc[6] = fmaf(w, __uint_as_float(u.w << 16),         acc[6]);
            acc[7] = fmaf(w, __uint_as_float(u.w & 0xffff0000u), acc[7]);
        }
        __syncthreads();
    }

    // combine 8 group-partials, then head-mean + residual + LN + ReLU
    #pragma unroll
    for (int i = 0; i < 8; ++i) flds[gp][8 * l + i] = acc[i];
    __syncthreads();
    {
        float s = 0.f;
        #pragma unroll
        for (int g8 = 0; g8 < 8; ++g8) s += flds[g8][t];
        flds[0][t] = s;            // each address owned by exactly one thread
    }
    __syncthreads();
    if (t < 64) {
        float v = flds[0][t] + flds[0][64 + t] + flds[0][128 + t] + flds[0][192 + t];
        v = 0.25f * v + resid[d * 64 + t];
        float s1 = v, s2 = v * v;
        #pragma unroll
        for (int o = 32; o > 0; o >>= 1) {
            s1 += __shfl_xor(s1, o, 64);
            s2 += __shfl_xor(s2, o, 64);
        }
        float mu  = s1 * (1.f / 64.f);
        float var = s2 * (1.f / 64.f) - mu * mu;
        float inv = 1.f / sqrtf(fmaxf(var, 0.f) + LN_EPS);
        float y = (v - mu) * inv * g[t] + b[t];
        y = fmaxf(y, 0.f);
        if (FINAL) hl2[t] = y;
        else       out[d * 64 + t] = y;
    }
    if (FINAL) {
        __syncthreads();
        if (t < 64) {
            float o = predb[t];
            for (int k = 0; k < 64; ++k) o = fmaf(hl2[k], predw[k * 64 + t], o);
            out[d * 64 + t] = o;
        }
    }
}

// ---------------------------------------------------------------------------
extern "C" void kernel_launch(void* const* d_in, const int* in_sizes, int n_in,
                              void* d_out, int out_size, void* d_ws, size_t ws_size,
                              hipStream_t stream)
{
    const float* feats = (const float*)d_in[0];
    const int*   src   = (const int*)  d_in[1];
    const int*   dst   = (const int*)  d_in[2];
    const float* W0    = (const float*)d_in[3];
    const float* al0   = (const float*)d_in[4];
    const float* ar0   = (const float*)d_in[5];
    const float* resw0 = (const float*)d_in[6];
    const float* resb0 = (const float*)d_in[7];
    const float* g0    = (const float*)d_in[8];
    const float* b0    = (const float*)d_in[9];
    const float* W1    = (const float*)d_in[10];
    const float* al1   = (const float*)d_in[11];
    const float* ar1   = (const float*)d_in[12];
    const float* resw1 = (const float*)d_in[13];
    const float* resb1 = (const float*)d_in[14];
    const float* g1    = (const float*)d_in[15];
    const float* b1    = (const float*)d_in[16];
    const float* predw = (const float*)d_in[17];
    const float* predb = (const float*)d_in[18];
    float* out = (float*)d_out;

    char* ws = (char*)d_ws;
    int*   rp = (int*)ws;                                   // (N+1) ints
    __hip_bfloat16* fs = (__hip_bfloat16*)(ws + 200192);    // N*256 bf16
    float* el    = (float*)((char*)fs + (size_t)N_NODES * 256 * 2);
    float* er    = el + (size_t)N_NODES * 4;
    float* resid = er + (size_t)N_NODES * 4;
    float* h1    = resid + (size_t)N_NODES * 64;

    k_rowptr<<<(N_NODES + 1 + 255) / 256, 256, 0, stream>>>(dst, rp);

    k_gemm<128><<<N_NODES / 16, 256, 0, stream>>>(
        feats, W0, al0, ar0, resw0, resb0, fs, el, er, resid);
    k_agg<false><<<N_NODES, 256, 0, stream>>>(
        rp, src, (const unsigned int*)fs, el, er, resid, g0, b0,
        nullptr, nullptr, h1);

    k_gemm<64><<<N_NODES / 16, 256, 0, stream>>>(
        h1, W1, al1, ar1, resw1, resb1, fs, el, er, resid);
    k_agg<true><<<N_NODES, 256, 0, stream>>>(
        rp, src, (const unsigned int*)fs, el, er, resid, g1, b1,
        predw, predb, out);
}

// Round 6
// 439.036 us; speedup vs baseline: 1.4638x; 1.2954x over previous
//
#include <hip/hip_runtime.h>
#include <hip/hip_bf16.h>

#define N_NODES 50000
#define E_EDGES 800000
#define NH 4
#define NEG_SLOPE 0.2f
#define LN_EPS 1e-5f

// ---------------------------------------------------------------------------
// CSR row_ptr from sorted dst via per-node lower_bound (no atomics).
// ---------------------------------------------------------------------------
__global__ void k_rowptr(const int* __restrict__ dst, int* __restrict__ rp) {
    int d = blockIdx.x * blockDim.x + threadIdx.x;
    if (d > N_NODES) return;
    int lo = 0, hi = E_EDGES;
    while (lo < hi) {
        int mid = (lo + hi) >> 1;
        if (dst[mid] < d) lo = mid + 1; else hi = mid;
    }
    rp[d] = lo;
}

// ---------------------------------------------------------------------------
// Node GEMM: fs[N,256] = h @ W (stored bf16), el/er[N,4] fp32,
// resid[N,64] = h @ resw + resb.  16 nodes / 256-thread block.
// ---------------------------------------------------------------------------
template<int K>
__global__ __launch_bounds__(256) void k_gemm(
    const float* __restrict__ hin, const float* __restrict__ W,
    const float* __restrict__ al, const float* __restrict__ ar,
    const float* __restrict__ resw, const float* __restrict__ resb,
    __hip_bfloat16* __restrict__ fs, float* __restrict__ el,
    float* __restrict__ er, float* __restrict__ resid)
{
    __shared__ __align__(16) float hl[K * 16];   // [k][node] layout
    const int n0 = blockIdx.x * 16;
    const int t  = threadIdx.x;

    for (int idx = t; idx < 16 * K; idx += 256) {
        int n = idx / K, k = idx - n * K;
        hl[k * 16 + n] = hin[(long long)(n0 + n) * K + k];   // 50000 % 16 == 0
    }
    __syncthreads();

    float acc[16];
    #pragma unroll
    for (int n = 0; n < 16; ++n) acc[n] = 0.f;

    #pragma unroll 2
    for (int k = 0; k < K; ++k) {
        float w = W[k * 256 + t];
        #pragma unroll
        for (int c = 0; c < 4; ++c) {
            const float4 a = *(const float4*)&hl[k * 16 + 4 * c];
            acc[4*c+0] = fmaf(a.x, w, acc[4*c+0]);
            acc[4*c+1] = fmaf(a.y, w, acc[4*c+1]);
            acc[4*c+2] = fmaf(a.z, w, acc[4*c+2]);
            acc[4*c+3] = fmaf(a.w, w, acc[4*c+3]);
        }
    }

    const int h = t >> 6, lane = t & 63;

    #pragma unroll
    for (int n = 0; n < 16; ++n)
        fs[(long long)(n0 + n) * 256 + t] = __float2bfloat16(acc[n]);

    // el/er from fp32 accumulators: wave h reduces its 64 lanes
    float alc = al[t], arc = ar[t];
    float e_l[16], e_r[16];
    #pragma unroll
    for (int n = 0; n < 16; ++n) { e_l[n] = acc[n] * alc; e_r[n] = acc[n] * arc; }
    #pragma unroll
    for (int o = 32; o > 0; o >>= 1) {
        #pragma unroll
        for (int n = 0; n < 16; ++n) {
            e_l[n] += __shfl_xor(e_l[n], o, 64);
            e_r[n] += __shfl_xor(e_r[n], o, 64);
        }
    }
    if (lane == 0) {
        #pragma unroll
        for (int n = 0; n < 16; ++n) {
            el[(n0 + n) * NH + h] = e_l[n];
            er[(n0 + n) * NH + h] = e_r[n];
        }
    }

    // resid: thread (h, lane) -> col = lane, nodes {h, h+4, h+8, h+12}
    float r[4] = {0.f, 0.f, 0.f, 0.f};
    for (int k = 0; k < K; ++k) {
        float w = resw[k * 64 + lane];
        #pragma unroll
        for (int j = 0; j < 4; ++j)
            r[j] = fmaf(hl[k * 16 + h + 4 * j], w, r[j]);
    }
    float bb = resb[lane];
    #pragma unroll
    for (int j = 0; j < 4; ++j)
        resid[(long long)(n0 + h + 4 * j) * 64 + lane] = r[j] + bb;
}

// ---------------------------------------------------------------------------
// One WAVE per destination node; 4 nodes per block; NO block barriers.
// Single pass: lane j computes exp(leaky(el[src[j]]+er[d])) for all 4 heads
// (float4), stages weight+src in wave-private LDS; the two 32-lane halves
// then gather fs rows (uint4 = 16B/lane, 2 edges in flight).  Softmax
// denominators reduced once at the end (no max-shift: logits are O(5)).
// Epilogue (head-mean, LN, ReLU, pred-head) via shfl butterflies.
// ---------------------------------------------------------------------------
template<bool FINAL>
__global__ __launch_bounds__(256) void k_agg(
    const int* __restrict__ rp, const int* __restrict__ src,
    const unsigned int* __restrict__ fs_u,   // [N][128] uints = 256 bf16
    const float* __restrict__ el, const float* __restrict__ er,
    const float* __restrict__ resid,
    const float* __restrict__ g, const float* __restrict__ b,
    const float* __restrict__ predw, const float* __restrict__ predb,
    float* __restrict__ out)
{
    __shared__ __align__(16) float aw[4][64][4];  // per-wave edge weights
    __shared__ int   sjw[4][64];                  // per-wave edge sources
    __shared__ float ylds[4][64];                 // FINAL matvec staging

    const int t    = threadIdx.x;
    const int wv   = t >> 6;
    const int lane = t & 63;
    const int d    = blockIdx.x * 4 + wv;
    const int l    = lane & 31;      // owns cols 8l..8l+7
    const int h2   = lane >> 5;      // half-wave id
    const int hh   = l >> 3;         // head of owned cols

    const int start = rp[d], end = rp[d + 1];
    const float4 er4 = *(const float4*)(er + d * NH);

    float4 s4 = make_float4(0.f, 0.f, 0.f, 0.f);
    float acc[8];
    #pragma unroll
    for (int i = 0; i < 8; ++i) acc[i] = 0.f;

    for (int cs = start; cs < end; cs += 64) {
        const int cnt = min(64, end - cs);
        int   sj = 0;
        float4 a4 = make_float4(0.f, 0.f, 0.f, 0.f);
        if (lane < cnt) {
            sj = src[cs + lane];
            const float4 el4 = *(const float4*)(el + sj * NH);
            float ex = el4.x + er4.x; ex = ex > 0.f ? ex : NEG_SLOPE * ex;
            float ey = el4.y + er4.y; ey = ey > 0.f ? ey : NEG_SLOPE * ey;
            float ez = el4.z + er4.z; ez = ez > 0.f ? ez : NEG_SLOPE * ez;
            float ew = el4.w + er4.w; ew = ew > 0.f ? ew : NEG_SLOPE * ew;
            a4.x = __expf(ex); a4.y = __expf(ey);
            a4.z = __expf(ez); a4.w = __expf(ew);
            s4.x += a4.x; s4.y += a4.y; s4.z += a4.z; s4.w += a4.w;
        }
        sjw[wv][lane] = sj;
        *(float4*)&aw[wv][lane][0] = a4;
        // wave-internal LDS ordering (compiler emits lgkmcnt waits)
        for (int jj = 0; jj < cnt; jj += 2) {
            const int j2 = jj + h2;
            if (j2 < cnt) {
                const float w = aw[wv][j2][hh];
                const int   s = sjw[wv][j2];
                const uint4 u = *((const uint4*)(fs_u + (size_t)s * 128) + l);
                acc[0] = fmaf(w, __uint_as_float(u.x << 16),         acc[0]);
                acc[1] = fmaf(w, __uint_as_float(u.x & 0xffff0000u), acc[1]);
                acc[2] = fmaf(w, __uint_as_float(u.y << 16),         acc[2]);
                acc[3] = fmaf(w, __uint_as_float(u.y & 0xffff0000u), acc[3]);
                acc[4] = fmaf(w, __uint_as_float(u.z << 16),         acc[4]);
                acc[5] = fmaf(w, __uint_as_float(u.z & 0xffff0000u), acc[5]);
                acc[6] = fmaf(w, __uint_as_float(u.w << 16),         acc[6]);
                acc[7] = fmaf(w, __uint_as_float(u.w & 0xffff0000u), acc[7]);
            }
        }
    }

    // combine the two half-wave partials (same cols in lanes l and l+32)
    #pragma unroll
    for (int i = 0; i < 8; ++i) acc[i] += __shfl_xor(acc[i], 32);

    // reduce softmax denominators across all 64 lanes
    #pragma unroll
    for (int o = 32; o > 0; o >>= 1) {
        s4.x += __shfl_xor(s4.x, o);
        s4.y += __shfl_xor(s4.y, o);
        s4.z += __shfl_xor(s4.z, o);
        s4.w += __shfl_xor(s4.w, o);
    }
    const float rsx = s4.x > 0.f ? 1.f / s4.x : 0.f;
    const float rsy = s4.y > 0.f ? 1.f / s4.y : 0.f;
    const float rsz = s4.z > 0.f ? 1.f / s4.z : 0.f;
    const float rsw = s4.w > 0.f ? 1.f / s4.w : 0.f;
    const float rsh = hh == 0 ? rsx : hh == 1 ? rsy : hh == 2 ? rsz : rsw;
    #pragma unroll
    for (int i = 0; i < 8; ++i) acc[i] *= rsh;

    // head-mean butterfly: lanes {l, l^8, l^16, l^24} hold the 4 heads
    #pragma unroll
    for (int i = 0; i < 8; ++i) {
        acc[i] += __shfl_xor(acc[i], 8);
        acc[i] += __shfl_xor(acc[i], 16);
    }

    const int c0 = 8 * (l & 7);
    const float4 r0 = *(const float4*)(resid + (size_t)d * 64 + c0);
    const float4 r1 = *(const float4*)(resid + (size_t)d * 64 + c0 + 4);
    float v[8];
    v[0] = 0.25f * acc[0] + r0.x;  v[1] = 0.25f * acc[1] + r0.y;
    v[2] = 0.25f * acc[2] + r0.z;  v[3] = 0.25f * acc[3] + r0.w;
    v[4] = 0.25f * acc[4] + r1.x;  v[5] = 0.25f * acc[5] + r1.y;
    v[6] = 0.25f * acc[6] + r1.z;  v[7] = 0.25f * acc[7] + r1.w;

    // LayerNorm stats over the 64 cols (8 families × 8 regs)
    float p = 0.f, p2 = 0.f;
    #pragma unroll
    for (int i = 0; i < 8; ++i) { p += v[i]; p2 += v[i] * v[i]; }
    #pragma unroll
    for (int o = 4; o > 0; o >>= 1) {
        p  += __shfl_xor(p,  o);
        p2 += __shfl_xor(p2, o);
    }
    const float mu  = p * (1.f / 64.f);
    const float var = p2 * (1.f / 64.f) - mu * mu;
    const float inv = 1.f / sqrtf(fmaxf(var, 0.f) + LN_EPS);

    const float4 g0v = *(const float4*)(g + c0);
    const float4 g1v = *(const float4*)(g + c0 + 4);
    const float4 b0v = *(const float4*)(b + c0);
    const float4 b1v = *(const float4*)(b + c0 + 4);
    float y[8];
    y[0] = fmaxf((v[0] - mu) * inv * g0v.x + b0v.x, 0.f);
    y[1] = fmaxf((v[1] - mu) * inv * g0v.y + b0v.y, 0.f);
    y[2] = fmaxf((v[2] - mu) * inv * g0v.z + b0v.z, 0.f);
    y[3] = fmaxf((v[3] - mu) * inv * g0v.w + b0v.w, 0.f);
    y[4] = fmaxf((v[4] - mu) * inv * g1v.x + b1v.x, 0.f);
    y[5] = fmaxf((v[5] - mu) * inv * g1v.y + b1v.y, 0.f);
    y[6] = fmaxf((v[6] - mu) * inv * g1v.z + b1v.z, 0.f);
    y[7] = fmaxf((v[7] - mu) * inv * g1v.w + b1v.w, 0.f);

    if (!FINAL) {
        if (lane < 8) {
            float4 o0 = make_float4(y[0], y[1], y[2], y[3]);
            float4 o1 = make_float4(y[4], y[5], y[6], y[7]);
            *(float4*)(out + (size_t)d * 64 + 8 * lane)     = o0;
            *(float4*)(out + (size_t)d * 64 + 8 * lane + 4) = o1;
        }
    } else {
        if (lane < 8) {
            #pragma unroll
            for (int i = 0; i < 8; ++i) ylds[wv][8 * lane + i] = y[i];
        }
        // wave-internal LDS ordering; then 64-lane matvec: lane = out col
        float o = predb[lane];
        #pragma unroll 4
        for (int k = 0; k < 64; ++k)
            o = fmaf(ylds[wv][k], predw[k * 64 + lane], o);
        out[(size_t)d * 64 + lane] = o;
    }
}

// ---------------------------------------------------------------------------
extern "C" void kernel_launch(void* const* d_in, const int* in_sizes, int n_in,
                              void* d_out, int out_size, void* d_ws, size_t ws_size,
                              hipStream_t stream)
{
    const float* feats = (const float*)d_in[0];
    const int*   src   = (const int*)  d_in[1];
    const int*   dst   = (const int*)  d_in[2];
    const float* W0    = (const float*)d_in[3];
    const float* al0   = (const float*)d_in[4];
    const float* ar0   = (const float*)d_in[5];
    const float* resw0 = (const float*)d_in[6];
    const float* resb0 = (const float*)d_in[7];
    const float* g0    = (const float*)d_in[8];
    const float* b0    = (const float*)d_in[9];
    const float* W1    = (const float*)d_in[10];
    const float* al1   = (const float*)d_in[11];
    const float* ar1   = (const float*)d_in[12];
    const float* resw1 = (const float*)d_in[13];
    const float* resb1 = (const float*)d_in[14];
    const float* g1    = (const float*)d_in[15];
    const float* b1    = (const float*)d_in[16];
    const float* predw = (const float*)d_in[17];
    const float* predb = (const float*)d_in[18];
    float* out = (float*)d_out;

    char* ws = (char*)d_ws;
    int*   rp = (int*)ws;                                   // (N+1) ints
    __hip_bfloat16* fs = (__hip_bfloat16*)(ws + 200192);    // N*256 bf16
    float* el    = (float*)((char*)fs + (size_t)N_NODES * 256 * 2);
    float* er    = el + (size_t)N_NODES * 4;
    float* resid = er + (size_t)N_NODES * 4;
    float* h1    = resid + (size_t)N_NODES * 64;

    k_rowptr<<<(N_NODES + 1 + 255) / 256, 256, 0, stream>>>(dst, rp);

    k_gemm<128><<<N_NODES / 16, 256, 0, stream>>>(
        feats, W0, al0, ar0, resw0, resb0, fs, el, er, resid);
    k_agg<false><<<N_NODES / 4, 256, 0, stream>>>(
        rp, src, (const unsigned int*)fs, el, er, resid, g0, b0,
        nullptr, nullptr, h1);

    k_gemm<64><<<N_NODES / 16, 256, 0, stream>>>(
        h1, W1, al1, ar1, resw1, resb1, fs, el, er, resid);
    k_agg<true><<<N_NODES / 4, 256, 0, stream>>>(
        rp, src, (const unsigned int*)fs, el, er, resid, g1, b1,
        predw, predb, out);
}

// Round 8
// 387.202 us; speedup vs baseline: 1.6597x; 1.1339x over previous
//
#include <hip/hip_runtime.h>
#include <hip/hip_bf16.h>

#define N_NODES 50000
#define E_EDGES 800000
#define NH 4
#define NEG_SLOPE 0.2f
#define LN_EPS 1e-5f

__device__ __forceinline__ unsigned short f2bf(float x) {
    __hip_bfloat16 h = __float2bfloat16(x);
    unsigned short u;
    __builtin_memcpy(&u, &h, sizeof(u));
    return u;
}

// ---------------------------------------------------------------------------
// CSR row_ptr from sorted dst via per-node lower_bound (no atomics).
// ---------------------------------------------------------------------------
__global__ void k_rowptr(const int* __restrict__ dst, int* __restrict__ rp) {
    int d = blockIdx.x * blockDim.x + threadIdx.x;
    if (d > N_NODES) return;
    int lo = 0, hi = E_EDGES;
    while (lo < hi) {
        int mid = (lo + hi) >> 1;
        if (dst[mid] < d) lo = mid + 1; else hi = mid;
    }
    rp[d] = lo;
}

// ---------------------------------------------------------------------------
// Node GEMM: fs[N,256] = h @ W (stored bf16), el/er[N,4] fp32,
// resid[N,64] = h @ resw + resb.  16 nodes / 256-thread block.
// Thread t: cols 4c..4c+3 (c=t&63) x nodes 4g..4g+3 (g=t>>6, wave id).
// Per k: one float4 W load + one broadcast b128 LDS read + 16 FMA.
// ---------------------------------------------------------------------------
template<int K>
__global__ __launch_bounds__(256) void k_gemm(
    const float* __restrict__ hin, const float* __restrict__ W,
    const float* __restrict__ al, const float* __restrict__ ar,
    const float* __restrict__ resw, const float* __restrict__ resb,
    __hip_bfloat16* __restrict__ fs, float* __restrict__ el,
    float* __restrict__ er, float* __restrict__ resid)
{
    __shared__ __align__(16) float hl[K * 16];   // [k][node] layout
    const int n0 = blockIdx.x * 16;
    const int t  = threadIdx.x;

    for (int idx = t; idx < 16 * K; idx += 256) {
        int n = idx / K, k = idx - n * K;
        hl[k * 16 + n] = hin[(long long)(n0 + n) * K + k];   // 50000 % 16 == 0
    }
    __syncthreads();

    const int c  = t & 63;     // column group: cols 4c..4c+3
    const int g  = t >> 6;     // wave id = node group: nodes 4g..4g+3
    const int c4 = 4 * c;

    float4 acc[4];             // acc[j] = cols 4c..4c+3 of node 4g+j
    #pragma unroll
    for (int j = 0; j < 4; ++j) acc[j] = make_float4(0.f, 0.f, 0.f, 0.f);

    #pragma unroll 4
    for (int k = 0; k < K; ++k) {
        const float4 w4 = *(const float4*)&W[k * 256 + c4];
        const float4 a4 = *(const float4*)&hl[k * 16 + 4 * g];
        acc[0].x = fmaf(w4.x, a4.x, acc[0].x);
        acc[0].y = fmaf(w4.y, a4.x, acc[0].y);
        acc[0].z = fmaf(w4.z, a4.x, acc[0].z);
        acc[0].w = fmaf(w4.w, a4.x, acc[0].w);
        acc[1].x = fmaf(w4.x, a4.y, acc[1].x);
        acc[1].y = fmaf(w4.y, a4.y, acc[1].y);
        acc[1].z = fmaf(w4.z, a4.y, acc[1].z);
        acc[1].w = fmaf(w4.w, a4.y, acc[1].w);
        acc[2].x = fmaf(w4.x, a4.z, acc[2].x);
        acc[2].y = fmaf(w4.y, a4.z, acc[2].y);
        acc[2].z = fmaf(w4.z, a4.z, acc[2].z);
        acc[2].w = fmaf(w4.w, a4.z, acc[2].w);
        acc[3].x = fmaf(w4.x, a4.w, acc[3].x);
        acc[3].y = fmaf(w4.y, a4.w, acc[3].y);
        acc[3].z = fmaf(w4.z, a4.w, acc[3].z);
        acc[3].w = fmaf(w4.w, a4.w, acc[3].w);
    }

    // fs store: per node, 4 cols packed as bf16 (8B coalesced stores)
    #pragma unroll
    for (int j = 0; j < 4; ++j) {
        const int node = n0 + 4 * g + j;
        ushort4 pk;
        pk.x = f2bf(acc[j].x);
        pk.y = f2bf(acc[j].y);
        pk.z = f2bf(acc[j].z);
        pk.w = f2bf(acc[j].w);
        *(ushort4*)&fs[(long long)node * 256 + c4] = pk;
    }

    // el/er: partial dot over this thread's 4 cols; 16-lane segmented
    // reduce (lanes c=16h..16h+15 all belong to head h).
    {
        const float4 al4 = *(const float4*)&al[c4];
        const float4 ar4 = *(const float4*)&ar[c4];
        float e_l[4], e_r[4];
        #pragma unroll
        for (int j = 0; j < 4; ++j) {
            e_l[j] = acc[j].x * al4.x + acc[j].y * al4.y
                   + acc[j].z * al4.z + acc[j].w * al4.w;
            e_r[j] = acc[j].x * ar4.x + acc[j].y * ar4.y
                   + acc[j].z * ar4.z + acc[j].w * ar4.w;
        }
        #pragma unroll
        for (int o = 8; o > 0; o >>= 1) {
            #pragma unroll
            for (int j = 0; j < 4; ++j) {
                e_l[j] += __shfl_xor(e_l[j], o, 64);
                e_r[j] += __shfl_xor(e_r[j], o, 64);
            }
        }
        if ((c & 15) == 0) {
            const int h = c >> 4;
            #pragma unroll
            for (int j = 0; j < 4; ++j) {
                const int node = n0 + 4 * g + j;
                el[node * NH + h] = e_l[j];
                er[node * NH + h] = e_r[j];
            }
        }
    }

    // resid: thread (g, c) -> col = c, nodes {g, g+4, g+8, g+12}
    float r[4] = {0.f, 0.f, 0.f, 0.f};
    for (int k = 0; k < K; ++k) {
        float w = resw[k * 64 + c];
        #pragma unroll
        for (int j = 0; j < 4; ++j)
            r[j] = fmaf(hl[k * 16 + g + 4 * j], w, r[j]);
    }
    float bb = resb[c];
    #pragma unroll
    for (int j = 0; j < 4; ++j)
        resid[(long long)(n0 + g + 4 * j) * 64 + c] = r[j] + bb;
}

// ---------------------------------------------------------------------------
// One WAVE per destination node; 4 nodes per block; NO block barriers.
// Single pass: lane j computes exp(leaky(el[src[j]]+er[d])) for all 4 heads
// (float4), stages weight+src in wave-private LDS; the two 32-lane halves
// then gather fs rows (uint4 = 16B/lane, 2 edges in flight).  Softmax
// denominators reduced once at the end (no max-shift: logits are O(5)).
// Epilogue (head-mean, LN, ReLU, pred-head) via shfl butterflies.
// ---------------------------------------------------------------------------
template<bool FINAL>
__global__ __launch_bounds__(256) void k_agg(
    const int* __restrict__ rp, const int* __restrict__ src,
    const unsigned int* __restrict__ fs_u,   // [N][128] uints = 256 bf16
    const float* __restrict__ el, const float* __restrict__ er,
    const float* __restrict__ resid,
    const float* __restrict__ g, const float* __restrict__ b,
    const float* __restrict__ predw, const float* __restrict__ predb,
    float* __restrict__ out)
{
    __shared__ __align__(16) float aw[4][64][4];  // per-wave edge weights
    __shared__ int   sjw[4][64];                  // per-wave edge sources
    __shared__ float ylds[4][64];                 // FINAL matvec staging

    const int t    = threadIdx.x;
    const int wv   = t >> 6;
    const int lane = t & 63;
    const int d    = blockIdx.x * 4 + wv;
    const int l    = lane & 31;      // owns cols 8l..8l+7
    const int h2   = lane >> 5;      // half-wave id
    const int hh   = l >> 3;         // head of owned cols

    const int start = rp[d], end = rp[d + 1];
    const float4 er4 = *(const float4*)(er + d * NH);

    float4 s4 = make_float4(0.f, 0.f, 0.f, 0.f);
    float acc[8];
    #pragma unroll
    for (int i = 0; i < 8; ++i) acc[i] = 0.f;

    for (int cs = start; cs < end; cs += 64) {
        const int cnt = min(64, end - cs);
        int   sj = 0;
        float4 a4 = make_float4(0.f, 0.f, 0.f, 0.f);
        if (lane < cnt) {
            sj = src[cs + lane];
            const float4 el4 = *(const float4*)(el + sj * NH);
            float ex = el4.x + er4.x; ex = ex > 0.f ? ex : NEG_SLOPE * ex;
            float ey = el4.y + er4.y; ey = ey > 0.f ? ey : NEG_SLOPE * ey;
            float ez = el4.z + er4.z; ez = ez > 0.f ? ez : NEG_SLOPE * ez;
            float ew = el4.w + er4.w; ew = ew > 0.f ? ew : NEG_SLOPE * ew;
            a4.x = __expf(ex); a4.y = __expf(ey);
            a4.z = __expf(ez); a4.w = __expf(ew);
            s4.x += a4.x; s4.y += a4.y; s4.z += a4.z; s4.w += a4.w;
        }
        sjw[wv][lane] = sj;
        *(float4*)&aw[wv][lane][0] = a4;
        // wave-internal LDS ordering (compiler emits lgkmcnt waits)
        for (int jj = 0; jj < cnt; jj += 2) {
            const int j2 = jj + h2;
            if (j2 < cnt) {
                const float w = aw[wv][j2][hh];
                const int   s = sjw[wv][j2];
                const uint4 u = *((const uint4*)(fs_u + (size_t)s * 128) + l);
                acc[0] = fmaf(w, __uint_as_float(u.x << 16),         acc[0]);
                acc[1] = fmaf(w, __uint_as_float(u.x & 0xffff0000u), acc[1]);
                acc[2] = fmaf(w, __uint_as_float(u.y << 16),         acc[2]);
                acc[3] = fmaf(w, __uint_as_float(u.y & 0xffff0000u), acc[3]);
                acc[4] = fmaf(w, __uint_as_float(u.z << 16),         acc[4]);
                acc[5] = fmaf(w, __uint_as_float(u.z & 0xffff0000u), acc[5]);
                acc[6] = fmaf(w, __uint_as_float(u.w << 16),         acc[6]);
                acc[7] = fmaf(w, __uint_as_float(u.w & 0xffff0000u), acc[7]);
            }
        }
    }

    // combine the two half-wave partials (same cols in lanes l and l+32)
    #pragma unroll
    for (int i = 0; i < 8; ++i) acc[i] += __shfl_xor(acc[i], 32);

    // reduce softmax denominators across all 64 lanes
    #pragma unroll
    for (int o = 32; o > 0; o >>= 1) {
        s4.x += __shfl_xor(s4.x, o);
        s4.y += __shfl_xor(s4.y, o);
        s4.z += __shfl_xor(s4.z, o);
        s4.w += __shfl_xor(s4.w, o);
    }
    const float rsx = s4.x > 0.f ? 1.f / s4.x : 0.f;
    const float rsy = s4.y > 0.f ? 1.f / s4.y : 0.f;
    const float rsz = s4.z > 0.f ? 1.f / s4.z : 0.f;
    const float rsw = s4.w > 0.f ? 1.f / s4.w : 0.f;
    const float rsh = hh == 0 ? rsx : hh == 1 ? rsy : hh == 2 ? rsz : rsw;
    #pragma unroll
    for (int i = 0; i < 8; ++i) acc[i] *= rsh;

    // head-mean butterfly: lanes {l, l^8, l^16, l^24} hold the 4 heads
    #pragma unroll
    for (int i = 0; i < 8; ++i) {
        acc[i] += __shfl_xor(acc[i], 8);
        acc[i] += __shfl_xor(acc[i], 16);
    }

    const int c0 = 8 * (l & 7);
    const float4 r0 = *(const float4*)(resid + (size_t)d * 64 + c0);
    const float4 r1 = *(const float4*)(resid + (size_t)d * 64 + c0 + 4);
    float v[8];
    v[0] = 0.25f * acc[0] + r0.x;  v[1] = 0.25f * acc[1] + r0.y;
    v[2] = 0.25f * acc[2] + r0.z;  v[3] = 0.25f * acc[3] + r0.w;
    v[4] = 0.25f * acc[4] + r1.x;  v[5] = 0.25f * acc[5] + r1.y;
    v[6] = 0.25f * acc[6] + r1.z;  v[7] = 0.25f * acc[7] + r1.w;

    // LayerNorm stats over the 64 cols (8 families × 8 regs)
    float p = 0.f, p2 = 0.f;
    #pragma unroll
    for (int i = 0; i < 8; ++i) { p += v[i]; p2 += v[i] * v[i]; }
    #pragma unroll
    for (int o = 4; o > 0; o >>= 1) {
        p  += __shfl_xor(p,  o);
        p2 += __shfl_xor(p2, o);
    }
    const float mu  = p * (1.f / 64.f);
    const float var = p2 * (1.f / 64.f) - mu * mu;
    const float inv = 1.f / sqrtf(fmaxf(var, 0.f) + LN_EPS);

    const float4 g0v = *(const float4*)(g + c0);
    const float4 g1v = *(const float4*)(g + c0 + 4);
    const float4 b0v = *(const float4*)(b + c0);
    const float4 b1v = *(const float4*)(b + c0 + 4);
    float y[8];
    y[0] = fmaxf((v[0] - mu) * inv * g0v.x + b0v.x, 0.f);
    y[1] = fmaxf((v[1] - mu) * inv * g0v.y + b0v.y, 0.f);
    y[2] = fmaxf((v[2] - mu) * inv * g0v.z + b0v.z, 0.f);
    y[3] = fmaxf((v[3] - mu) * inv * g0v.w + b0v.w, 0.f);
    y[4] = fmaxf((v[4] - mu) * inv * g1v.x + b1v.x, 0.f);
    y[5] = fmaxf((v[5] - mu) * inv * g1v.y + b1v.y, 0.f);
    y[6] = fmaxf((v[6] - mu) * inv * g1v.z + b1v.z, 0.f);
    y[7] = fmaxf((v[7] - mu) * inv * g1v.w + b1v.w, 0.f);

    if (!FINAL) {
        if (lane < 8) {
            float4 o0 = make_float4(y[0], y[1], y[2], y[3]);
            float4 o1 = make_float4(y[4], y[5], y[6], y[7]);
            *(float4*)(out + (size_t)d * 64 + 8 * lane)     = o0;
            *(float4*)(out + (size_t)d * 64 + 8 * lane + 4) = o1;
        }
    } else {
        if (lane < 8) {
            #pragma unroll
            for (int i = 0; i < 8; ++i) ylds[wv][8 * lane + i] = y[i];
        }
        // wave-internal LDS ordering; then 64-lane matvec: lane = out col
        float o = predb[lane];
        #pragma unroll 4
        for (int k = 0; k < 64; ++k)
            o = fmaf(ylds[wv][k], predw[k * 64 + lane], o);
        out[(size_t)d * 64 + lane] = o;
    }
}

// ---------------------------------------------------------------------------
extern "C" void kernel_launch(void* const* d_in, const int* in_sizes, int n_in,
                              void* d_out, int out_size, void* d_ws, size_t ws_size,
                              hipStream_t stream)
{
    const float* feats = (const float*)d_in[0];
    const int*   src   = (const int*)  d_in[1];
    const int*   dst   = (const int*)  d_in[2];
    const float* W0    = (const float*)d_in[3];
    const float* al0   = (const float*)d_in[4];
    const float* ar0   = (const float*)d_in[5];
    const float* resw0 = (const float*)d_in[6];
    const float* resb0 = (const float*)d_in[7];
    const float* g0    = (const float*)d_in[8];
    const float* b0    = (const float*)d_in[9];
    const float* W1    = (const float*)d_in[10];
    const float* al1   = (const float*)d_in[11];
    const float* ar1   = (const float*)d_in[12];
    const float* resw1 = (const float*)d_in[13];
    const float* resb1 = (const float*)d_in[14];
    const float* g1    = (const float*)d_in[15];
    const float* b1    = (const float*)d_in[16];
    const float* predw = (const float*)d_in[17];
    const float* predb = (const float*)d_in[18];
    float* out = (float*)d_out;

    char* ws = (char*)d_ws;
    int*   rp = (int*)ws;                                   // (N+1) ints
    __hip_bfloat16* fs = (__hip_bfloat16*)(ws + 200192);    // N*256 bf16
    float* el    = (float*)((char*)fs + (size_t)N_NODES * 256 * 2);
    float* er    = el + (size_t)N_NODES * 4;
    float* resid = er + (size_t)N_NODES * 4;
    float* h1    = resid + (size_t)N_NODES * 64;

    k_rowptr<<<(N_NODES + 1 + 255) / 256, 256, 0, stream>>>(dst, rp);

    k_gemm<128><<<N_NODES / 16, 256, 0, stream>>>(
        feats, W0, al0, ar0, resw0, resb0, fs, el, er, resid);
    k_agg<false><<<N_NODES / 4, 256, 0, stream>>>(
        rp, src, (const unsigned int*)fs, el, er, resid, g0, b0,
        nullptr, nullptr, h1);

    k_gemm<64><<<N_NODES / 16, 256, 0, stream>>>(
        h1, W1, al1, ar1, resw1, resb1, fs, el, er, resid);
    k_agg<true><<<N_NODES / 4, 256, 0, stream>>>(
        rp, src, (const unsigned int*)fs, el, er, resid, g1, b1,
        predw, predb, out);
}

// Round 10
// 367.413 us; speedup vs baseline: 1.7491x; 1.0539x over previous
//
#include <hip/hip_runtime.h>
#include <hip/hip_bf16.h>

#define N_NODES 50000
#define E_EDGES 800000
#define NH 4
#define NEG_SLOPE 0.2f
#define LN_EPS 1e-5f

__device__ __forceinline__ unsigned short f2bf(float x) {
    __hip_bfloat16 h = __float2bfloat16(x);
    unsigned short u;
    __builtin_memcpy(&u, &h, sizeof(u));
    return u;
}

// ---------------------------------------------------------------------------
// CSR row_ptr from sorted dst via per-node lower_bound (no atomics).
// ---------------------------------------------------------------------------
__global__ void k_rowptr(const int* __restrict__ dst, int* __restrict__ rp) {
    int d = blockIdx.x * blockDim.x + threadIdx.x;
    if (d > N_NODES) return;
    int lo = 0, hi = E_EDGES;
    while (lo < hi) {
        int mid = (lo + hi) >> 1;
        if (dst[mid] < d) lo = mid + 1; else hi = mid;
    }
    rp[d] = lo;
}

// ---------------------------------------------------------------------------
// Node GEMM: fs[N,256] = h @ W (stored bf16), el/er[N,4] fp32,
// resid[N,64] = h @ resw + resb.   32 nodes / 256-thread block.
// Thread t: cols 4c..4c+3 (c=t&63) x nodes 8g..8g+7 (g=t>>6, wave id).
// Per k: 1 float4 W load + 1 scalar resw load + 8 broadcast LDS reads +
// 40 FMA (32 main + 8 resid).  hl padded to 33 -> staging conflict-free.
// ---------------------------------------------------------------------------
template<int K>
__global__ __launch_bounds__(256) void k_gemm(
    const float* __restrict__ hin, const float* __restrict__ W,
    const float* __restrict__ al, const float* __restrict__ ar,
    const float* __restrict__ resw, const float* __restrict__ resb,
    __hip_bfloat16* __restrict__ fs, float* __restrict__ el,
    float* __restrict__ er, float* __restrict__ resid)
{
    __shared__ float hl[K * 33];          // [k][node], pad 33: banks (k+n)%32
    const int n0 = blockIdx.x * 32;
    const int t  = threadIdx.x;

    for (int idx = t; idx < 32 * K; idx += 256) {
        int n = idx / K, k = idx - n * K;
        int node = min(n0 + n, N_NODES - 1);     // clamp for tail block
        hl[k * 33 + n] = hin[(long long)node * K + k];
    }
    __syncthreads();

    const int c  = t & 63;     // column group: cols 4c..4c+3
    const int g  = t >> 6;     // wave id = node group: nodes 8g..8g+7
    const int c4 = 4 * c;

    float4 acc[8];             // acc[j] = cols 4c..4c+3 of node n0+8g+j
    float  r[8];               // resid col c of node n0+8g+j
    #pragma unroll
    for (int j = 0; j < 8; ++j) {
        acc[j] = make_float4(0.f, 0.f, 0.f, 0.f);
        r[j] = 0.f;
    }

    #pragma unroll 2
    for (int k = 0; k < K; ++k) {
        const float4 w4 = *(const float4*)&W[k * 256 + c4];
        const float  rw = resw[k * 64 + c];
        float a[8];
        #pragma unroll
        for (int j = 0; j < 8; ++j) a[j] = hl[k * 33 + 8 * g + j];
        #pragma unroll
        for (int j = 0; j < 8; ++j) {
            acc[j].x = fmaf(w4.x, a[j], acc[j].x);
            acc[j].y = fmaf(w4.y, a[j], acc[j].y);
            acc[j].z = fmaf(w4.z, a[j], acc[j].z);
            acc[j].w = fmaf(w4.w, a[j], acc[j].w);
            r[j]     = fmaf(rw,   a[j], r[j]);
        }
    }

    // fs store: per node, 4 cols packed as bf16 (8B coalesced stores)
    #pragma unroll
    for (int j = 0; j < 8; ++j) {
        const int node = n0 + 8 * g + j;
        if (node < N_NODES) {
            ushort4 pk;
            pk.x = f2bf(acc[j].x);
            pk.y = f2bf(acc[j].y);
            pk.z = f2bf(acc[j].z);
            pk.w = f2bf(acc[j].w);
            *(ushort4*)&fs[(long long)node * 256 + c4] = pk;
        }
    }

    // resid store
    {
        const float bb = resb[c];
        #pragma unroll
        for (int j = 0; j < 8; ++j) {
            const int node = n0 + 8 * g + j;
            if (node < N_NODES)
                resid[(long long)node * 64 + c] = r[j] + bb;
        }
    }

    // el/er: partial dot over this thread's 4 cols; 16-lane segmented
    // reduce (lanes c=16h..16h+15 all belong to head h).
    {
        const float4 al4 = *(const float4*)&al[c4];
        const float4 ar4 = *(const float4*)&ar[c4];
        float e_l[8], e_r[8];
        #pragma unroll
        for (int j = 0; j < 8; ++j) {
            e_l[j] = acc[j].x * al4.x + acc[j].y * al4.y
                   + acc[j].z * al4.z + acc[j].w * al4.w;
            e_r[j] = acc[j].x * ar4.x + acc[j].y * ar4.y
                   + acc[j].z * ar4.z + acc[j].w * ar4.w;
        }
        #pragma unroll
        for (int o = 8; o > 0; o >>= 1) {
            #pragma unroll
            for (int j = 0; j < 8; ++j) {
                e_l[j] += __shfl_xor(e_l[j], o, 64);
                e_r[j] += __shfl_xor(e_r[j], o, 64);
            }
        }
        if ((c & 15) == 0) {
            const int h = c >> 4;
            #pragma unroll
            for (int j = 0; j < 8; ++j) {
                const int node = n0 + 8 * g + j;
                if (node < N_NODES) {
                    el[node * NH + h] = e_l[j];
                    er[node * NH + h] = e_r[j];
                }
            }
        }
    }
}

// ---------------------------------------------------------------------------
// One WAVE per destination node; 4 nodes per block; NO block barriers.
// Single pass: lane j computes exp(leaky(el[src[j]]+er[d])) for all 4 heads
// (float4), stages weight+src in wave-private LDS; the two 32-lane halves
// then gather fs rows (uint4 = 16B/lane, unroll 4 -> 4 gathers in flight).
// Softmax denominators reduced once at the end (no max-shift: logits O(5)).
// Epilogue (head-mean, LN, ReLU, pred-head) via shfl butterflies.
// ---------------------------------------------------------------------------
template<bool FINAL>
__global__ __launch_bounds__(256) void k_agg(
    const int* __restrict__ rp, const int* __restrict__ src,
    const unsigned int* __restrict__ fs_u,   // [N][128] uints = 256 bf16
    const float* __restrict__ el, const float* __restrict__ er,
    const float* __restrict__ resid,
    const float* __restrict__ g, const float* __restrict__ b,
    const float* __restrict__ predw, const float* __restrict__ predb,
    float* __restrict__ out)
{
    __shared__ __align__(16) float aw[4][64][4];  // per-wave edge weights
    __shared__ int   sjw[4][64];                  // per-wave edge sources
    __shared__ float ylds[4][64];                 // FINAL matvec staging

    const int t    = threadIdx.x;
    const int wv   = t >> 6;
    const int lane = t & 63;
    const int d    = blockIdx.x * 4 + wv;
    const int l    = lane & 31;      // owns cols 8l..8l+7
    const int h2   = lane >> 5;      // half-wave id
    const int hh   = l >> 3;         // head of owned cols

    const int start = rp[d], end = rp[d + 1];
    const float4 er4 = *(const float4*)(er + d * NH);

    float4 s4 = make_float4(0.f, 0.f, 0.f, 0.f);
    float acc[8];
    #pragma unroll
    for (int i = 0; i < 8; ++i) acc[i] = 0.f;

    for (int cs = start; cs < end; cs += 64) {
        const int cnt = min(64, end - cs);
        int   sj = 0;
        float4 a4 = make_float4(0.f, 0.f, 0.f, 0.f);
        if (lane < cnt) {
            sj = src[cs + lane];
            const float4 el4 = *(const float4*)(el + sj * NH);
            float ex = el4.x + er4.x; ex = ex > 0.f ? ex : NEG_SLOPE * ex;
            float ey = el4.y + er4.y; ey = ey > 0.f ? ey : NEG_SLOPE * ey;
            float ez = el4.z + er4.z; ez = ez > 0.f ? ez : NEG_SLOPE * ez;
            float ew = el4.w + er4.w; ew = ew > 0.f ? ew : NEG_SLOPE * ew;
            a4.x = __expf(ex); a4.y = __expf(ey);
            a4.z = __expf(ez); a4.w = __expf(ew);
            s4.x += a4.x; s4.y += a4.y; s4.z += a4.z; s4.w += a4.w;
        }
        sjw[wv][lane] = sj;
        *(float4*)&aw[wv][lane][0] = a4;
        // wave-internal LDS ordering (compiler emits lgkmcnt waits)
        #pragma unroll 4
        for (int jj = 0; jj < cnt; jj += 2) {
            const int j2 = jj + h2;
            if (j2 < cnt) {
                const float w = aw[wv][j2][hh];
                const int   s = sjw[wv][j2];
                const uint4 u = *((const uint4*)(fs_u + (size_t)s * 128) + l);
                acc[0] = fmaf(w, __uint_as_float(u.x << 16),         acc[0]);
                acc[1] = fmaf(w, __uint_as_float(u.x & 0xffff0000u), acc[1]);
                acc[2] = fmaf(w, __uint_as_float(u.y << 16),         acc[2]);
                acc[3] = fmaf(w, __uint_as_float(u.y & 0xffff0000u), acc[3]);
                acc[4] = fmaf(w, __uint_as_float(u.z << 16),         acc[4]);
                acc[5] = fmaf(w, __uint_as_float(u.z & 0xffff0000u), acc[5]);
                acc[6] = fmaf(w, __uint_as_float(u.w << 16),         acc[6]);
                acc[7] = fmaf(w, __uint_as_float(u.w & 0xffff0000u), acc[7]);
            }
        }
    }

    // combine the two half-wave partials (same cols in lanes l and l+32)
    #pragma unroll
    for (int i = 0; i < 8; ++i) acc[i] += __shfl_xor(acc[i], 32);

    // reduce softmax denominators across all 64 lanes
    #pragma unroll
    for (int o = 32; o > 0; o >>= 1) {
        s4.x += __shfl_xor(s4.x, o);
        s4.y += __shfl_xor(s4.y, o);
        s4.z += __shfl_xor(s4.z, o);
        s4.w += __shfl_xor(s4.w, o);
    }
    const float rsx = s4.x > 0.f ? 1.f / s4.x : 0.f;
    const float rsy = s4.y > 0.f ? 1.f / s4.y : 0.f;
    const float rsz = s4.z > 0.f ? 1.f / s4.z : 0.f;
    const float rsw = s4.w > 0.f ? 1.f / s4.w : 0.f;
    const float rsh = hh == 0 ? rsx : hh == 1 ? rsy : hh == 2 ? rsz : rsw;
    #pragma unroll
    for (int i = 0; i < 8; ++i) acc[i] *= rsh;

    // head-mean butterfly: lanes {l, l^8, l^16, l^24} hold the 4 heads
    #pragma unroll
    for (int i = 0; i < 8; ++i) {
        acc[i] += __shfl_xor(acc[i], 8);
        acc[i] += __shfl_xor(acc[i], 16);
    }

    const int c0 = 8 * (l & 7);
    const float4 r0 = *(const float4*)(resid + (size_t)d * 64 + c0);
    const float4 r1 = *(const float4*)(resid + (size_t)d * 64 + c0 + 4);
    float v[8];
    v[0] = 0.25f * acc[0] + r0.x;  v[1] = 0.25f * acc[1] + r0.y;
    v[2] = 0.25f * acc[2] + r0.z;  v[3] = 0.25f * acc[3] + r0.w;
    v[4] = 0.25f * acc[4] + r1.x;  v[5] = 0.25f * acc[5] + r1.y;
    v[6] = 0.25f * acc[6] + r1.z;  v[7] = 0.25f * acc[7] + r1.w;

    // LayerNorm stats over the 64 cols (8 families × 8 regs)
    float p = 0.f, p2 = 0.f;
    #pragma unroll
    for (int i = 0; i < 8; ++i) { p += v[i]; p2 += v[i] * v[i]; }
    #pragma unroll
    for (int o = 4; o > 0; o >>= 1) {
        p  += __shfl_xor(p,  o);
        p2 += __shfl_xor(p2, o);
    }
    const float mu  = p * (1.f / 64.f);
    const float var = p2 * (1.f / 64.f) - mu * mu;
    const float inv = 1.f / sqrtf(fmaxf(var, 0.f) + LN_EPS);

    const float4 g0v = *(const float4*)(g + c0);
    const float4 g1v = *(const float4*)(g + c0 + 4);
    const float4 b0v = *(const float4*)(b + c0);
    const float4 b1v = *(const float4*)(b + c0 + 4);
    float y[8];
    y[0] = fmaxf((v[0] - mu) * inv * g0v.x + b0v.x, 0.f);
    y[1] = fmaxf((v[1] - mu) * inv * g0v.y + b0v.y, 0.f);
    y[2] = fmaxf((v[2] - mu) * inv * g0v.z + b0v.z, 0.f);
    y[3] = fmaxf((v[3] - mu) * inv * g0v.w + b0v.w, 0.f);
    y[4] = fmaxf((v[4] - mu) * inv * g1v.x + b1v.x, 0.f);
    y[5] = fmaxf((v[5] - mu) * inv * g1v.y + b1v.y, 0.f);
    y[6] = fmaxf((v[6] - mu) * inv * g1v.z + b1v.z, 0.f);
    y[7] = fmaxf((v[7] - mu) * inv * g1v.w + b1v.w, 0.f);

    if (!FINAL) {
        if (lane < 8) {
            float4 o0 = make_float4(y[0], y[1], y[2], y[3]);
            float4 o1 = make_float4(y[4], y[5], y[6], y[7]);
            *(float4*)(out + (size_t)d * 64 + 8 * lane)     = o0;
            *(float4*)(out + (size_t)d * 64 + 8 * lane + 4) = o1;
        }
    } else {
        if (lane < 8) {
            #pragma unroll
            for (int i = 0; i < 8; ++i) ylds[wv][8 * lane + i] = y[i];
        }
        // wave-internal LDS ordering; then 64-lane matvec: lane = out col
        float o = predb[lane];
        #pragma unroll 4
        for (int k = 0; k < 64; ++k)
            o = fmaf(ylds[wv][k], predw[k * 64 + lane], o);
        out[(size_t)d * 64 + lane] = o;
    }
}

// ---------------------------------------------------------------------------
extern "C" void kernel_launch(void* const* d_in, const int* in_sizes, int n_in,
                              void* d_out, int out_size, void* d_ws, size_t ws_size,
                              hipStream_t stream)
{
    const float* feats = (const float*)d_in[0];
    const int*   src   = (const int*)  d_in[1];
    const int*   dst   = (const int*)  d_in[2];
    const float* W0    = (const float*)d_in[3];
    const float* al0   = (const float*)d_in[4];
    const float* ar0   = (const float*)d_in[5];
    const float* resw0 = (const float*)d_in[6];
    const float* resb0 = (const float*)d_in[7];
    const float* g0    = (const float*)d_in[8];
    const float* b0    = (const float*)d_in[9];
    const float* W1    = (const float*)d_in[10];
    const float* al1   = (const float*)d_in[11];
    const float* ar1   = (const float*)d_in[12];
    const float* resw1 = (const float*)d_in[13];
    const float* resb1 = (const float*)d_in[14];
    const float* g1    = (const float*)d_in[15];
    const float* b1    = (const float*)d_in[16];
    const float* predw = (const float*)d_in[17];
    const float* predb = (const float*)d_in[18];
    float* out = (float*)d_out;

    char* ws = (char*)d_ws;
    int*   rp = (int*)ws;                                   // (N+1) ints
    __hip_bfloat16* fs = (__hip_bfloat16*)(ws + 200192);    // N*256 bf16
    float* el    = (float*)((char*)fs + (size_t)N_NODES * 256 * 2);
    float* er    = el + (size_t)N_NODES * 4;
    float* resid = er + (size_t)N_NODES * 4;
    float* h1    = resid + (size_t)N_NODES * 64;

    k_rowptr<<<(N_NODES + 1 + 255) / 256, 256, 0, stream>>>(dst, rp);

    k_gemm<128><<<(N_NODES + 31) / 32, 256, 0, stream>>>(
        feats, W0, al0, ar0, resw0, resb0, fs, el, er, resid);
    k_agg<false><<<N_NODES / 4, 256, 0, stream>>>(
        rp, src, (const unsigned int*)fs, el, er, resid, g0, b0,
        nullptr, nullptr, h1);

    k_gemm<64><<<(N_NODES + 31) / 32, 256, 0, stream>>>(
        h1, W1, al1, ar1, resw1, resb1, fs, el, er, resid);
    k_agg<true><<<N_NODES / 4, 256, 0, stream>>>(
        rp, src, (const unsigned int*)fs, el, er, resid, g1, b1,
        predw, predb, out);
}

// Round 11
// 329.858 us; speedup vs baseline: 1.9483x; 1.1139x over previous
//
#include <hip/hip_runtime.h>
#include <hip/hip_bf16.h>

#define N_NODES 50000
#define E_EDGES 800000
#define NH 4
#define NEG_SLOPE 0.2f
#define LN_EPS 1e-5f

typedef short short8v __attribute__((ext_vector_type(8)));
typedef float f32x4  __attribute__((ext_vector_type(4)));

__device__ __forceinline__ unsigned short f2bf(float x) {
    __hip_bfloat16 h = __float2bfloat16(x);
    unsigned short u;
    __builtin_memcpy(&u, &h, sizeof(u));
    return u;
}

// ---------------------------------------------------------------------------
// CSR row_ptr from sorted dst via per-node lower_bound (no atomics).
// ---------------------------------------------------------------------------
__global__ void k_rowptr(const int* __restrict__ dst, int* __restrict__ rp) {
    int d = blockIdx.x * blockDim.x + threadIdx.x;
    if (d > N_NODES) return;
    int lo = 0, hi = E_EDGES;
    while (lo < hi) {
        int mid = (lo + hi) >> 1;
        if (dst[mid] < d) lo = mid + 1; else hi = mid;
    }
    rp[d] = lo;
}

// ---------------------------------------------------------------------------
// Weight prep: Vt[l][c][k] = bf16 of [W | resw][k][c]  (c in [0,320))
// Transposed so B-fragments (8 consecutive k per lane) are one 16B load.
// ---------------------------------------------------------------------------
__global__ void k_wprep(const float* __restrict__ W0, const float* __restrict__ rw0,
                        short* __restrict__ Vt0,
                        const float* __restrict__ W1, const float* __restrict__ rw1,
                        short* __restrict__ Vt1)
{
    int idx = blockIdx.x * 256 + threadIdx.x;
    if (idx < 320 * 128) {
        int c = idx >> 7, k = idx & 127;
        float v = (c < 256) ? W0[k * 256 + c] : rw0[k * 64 + (c - 256)];
        Vt0[c * 128 + k] = (short)f2bf(v);
    }
    int i1 = idx - 320 * 128;
    if (i1 >= 0 && i1 < 320 * 64) {
        int c = i1 >> 6, k = i1 & 63;
        float v = (c < 256) ? W1[k * 256 + c] : rw1[k * 64 + (c - 256)];
        Vt1[c * 64 + k] = (short)f2bf(v);
    }
}

// ---------------------------------------------------------------------------
// MFMA node GEMM: [16 nodes] x [320 cols] = fs(256, bf16) + resid(64, +resb),
// plus el/er.  4 waves; wave w owns head w's 64 cols (4 tiles) + resid tile.
// mfma_f32_16x16x32_bf16: A row=lane&15, k=(lane>>4)*8+j; B col=lane&15;
// D col=lane&15, row=(lane>>4)*4+reg  [learn_hip m89-verified].
// Since wave w's cols == head w, el/er reduce fully in-wave (shfl over
// lane&15 bits); lanes with (l&15)==0 hold rows (l>>4)*4+reg.
// ---------------------------------------------------------------------------
template<int K>
__global__ __launch_bounds__(256) void k_gemm(
    const float* __restrict__ hin, const short* __restrict__ Vt,
    const float* __restrict__ al, const float* __restrict__ ar,
    const float* __restrict__ resb,
    __hip_bfloat16* __restrict__ fs, float* __restrict__ el,
    float* __restrict__ er, float* __restrict__ resid)
{
    constexpr int KP = K + 1;            // pad: LDS banks (r + 8s) % 32, <=2-way
    __shared__ float hl[16 * KP];
    const int n0  = blockIdx.x * 16;     // 50000 % 16 == 0
    const int t   = threadIdx.x;
    const int w   = t >> 6;              // wave = head = col group
    const int l   = t & 63;
    const int c16 = l & 15;              // A-row / B,D-col within tile
    const int ks  = l >> 4;              // k-slice / D-row group

    for (int idx = t; idx < 16 * K; idx += 256) {
        int n = idx / K, k = idx % K;
        hl[n * KP + k] = hin[(long long)(n0 + n) * K + k];
    }
    __syncthreads();

    constexpr int NKB = K / 32;
    f32x4 acc[5];
    #pragma unroll
    for (int i = 0; i < 5; ++i) acc[i] = (f32x4){0.f, 0.f, 0.f, 0.f};

    #pragma unroll
    for (int kb = 0; kb < NKB; ++kb) {
        const int kbase = kb * 32 + ks * 8;
        short8v af;
        #pragma unroll
        for (int j = 0; j < 8; ++j)
            af[j] = (short)f2bf(hl[c16 * KP + kbase + j]);
        #pragma unroll
        for (int i = 0; i < 4; ++i) {
            const int cg = 64 * w + 16 * i + c16;
            short8v bf = *(const short8v*)(Vt + (size_t)cg * K + kbase);
            acc[i] = __builtin_amdgcn_mfma_f32_16x16x32_bf16(af, bf, acc[i], 0, 0, 0);
        }
        {
            const int cg = 256 + 16 * w + c16;
            short8v bf = *(const short8v*)(Vt + (size_t)cg * K + kbase);
            acc[4] = __builtin_amdgcn_mfma_f32_16x16x32_bf16(af, bf, acc[4], 0, 0, 0);
        }
    }

    // fs store + el/er partials
    float el_p[4] = {0.f, 0.f, 0.f, 0.f};
    float er_p[4] = {0.f, 0.f, 0.f, 0.f};
    #pragma unroll
    for (int i = 0; i < 4; ++i) {
        const int cg = 64 * w + 16 * i + c16;
        const float alv = al[cg], arv = ar[cg];
        #pragma unroll
        for (int reg = 0; reg < 4; ++reg) {
            const float v = acc[i][reg];
            const int node = n0 + ks * 4 + reg;
            fs[(size_t)node * 256 + cg] = __float2bfloat16(v);
            el_p[reg] = fmaf(v, alv, el_p[reg]);
            er_p[reg] = fmaf(v, arv, er_p[reg]);
        }
    }
    #pragma unroll
    for (int o = 1; o < 16; o <<= 1) {
        #pragma unroll
        for (int reg = 0; reg < 4; ++reg) {
            el_p[reg] += __shfl_xor(el_p[reg], o, 64);
            er_p[reg] += __shfl_xor(er_p[reg], o, 64);
        }
    }
    if (c16 == 0) {
        #pragma unroll
        for (int reg = 0; reg < 4; ++reg) {
            const int node = n0 + ks * 4 + reg;
            el[node * NH + w] = el_p[reg];
            er[node * NH + w] = er_p[reg];
        }
    }
    // resid tile
    {
        const int rc = 16 * w + c16;
        const float bb = resb[rc];
        #pragma unroll
        for (int reg = 0; reg < 4; ++reg) {
            const int node = n0 + ks * 4 + reg;
            resid[(size_t)node * 64 + rc] = acc[4][reg] + bb;
        }
    }
}

// ---------------------------------------------------------------------------
// One WAVE per destination node; 4 nodes per block; NO block barriers.
// (unchanged from R8/R10 — at the per-XCD compulsory-fetch wall)
// ---------------------------------------------------------------------------
template<bool FINAL>
__global__ __launch_bounds__(256) void k_agg(
    const int* __restrict__ rp, const int* __restrict__ src,
    const unsigned int* __restrict__ fs_u,   // [N][128] uints = 256 bf16
    const float* __restrict__ el, const float* __restrict__ er,
    const float* __restrict__ resid,
    const float* __restrict__ g, const float* __restrict__ b,
    const float* __restrict__ predw, const float* __restrict__ predb,
    float* __restrict__ out)
{
    __shared__ __align__(16) float aw[4][64][4];  // per-wave edge weights
    __shared__ int   sjw[4][64];                  // per-wave edge sources
    __shared__ float ylds[4][64];                 // FINAL matvec staging

    const int t    = threadIdx.x;
    const int wv   = t >> 6;
    const int lane = t & 63;
    const int d    = blockIdx.x * 4 + wv;
    const int l    = lane & 31;      // owns cols 8l..8l+7
    const int h2   = lane >> 5;      // half-wave id
    const int hh   = l >> 3;         // head of owned cols

    const int start = rp[d], end = rp[d + 1];
    const float4 er4 = *(const float4*)(er + d * NH);

    float4 s4 = make_float4(0.f, 0.f, 0.f, 0.f);
    float acc[8];
    #pragma unroll
    for (int i = 0; i < 8; ++i) acc[i] = 0.f;

    for (int cs = start; cs < end; cs += 64) {
        const int cnt = min(64, end - cs);
        int   sj = 0;
        float4 a4 = make_float4(0.f, 0.f, 0.f, 0.f);
        if (lane < cnt) {
            sj = src[cs + lane];
            const float4 el4 = *(const float4*)(el + sj * NH);
            float ex = el4.x + er4.x; ex = ex > 0.f ? ex : NEG_SLOPE * ex;
            float ey = el4.y + er4.y; ey = ey > 0.f ? ey : NEG_SLOPE * ey;
            float ez = el4.z + er4.z; ez = ez > 0.f ? ez : NEG_SLOPE * ez;
            float ew = el4.w + er4.w; ew = ew > 0.f ? ew : NEG_SLOPE * ew;
            a4.x = __expf(ex); a4.y = __expf(ey);
            a4.z = __expf(ez); a4.w = __expf(ew);
            s4.x += a4.x; s4.y += a4.y; s4.z += a4.z; s4.w += a4.w;
        }
        sjw[wv][lane] = sj;
        *(float4*)&aw[wv][lane][0] = a4;
        // wave-internal LDS ordering (compiler emits lgkmcnt waits)
        #pragma unroll 4
        for (int jj = 0; jj < cnt; jj += 2) {
            const int j2 = jj + h2;
            if (j2 < cnt) {
                const float w = aw[wv][j2][hh];
                const int   s = sjw[wv][j2];
                const uint4 u = *((const uint4*)(fs_u + (size_t)s * 128) + l);
                acc[0] = fmaf(w, __uint_as_float(u.x << 16),         acc[0]);
                acc[1] = fmaf(w, __uint_as_float(u.x & 0xffff0000u), acc[1]);
                acc[2] = fmaf(w, __uint_as_float(u.y << 16),         acc[2]);
                acc[3] = fmaf(w, __uint_as_float(u.y & 0xffff0000u), acc[3]);
                acc[4] = fmaf(w, __uint_as_float(u.z << 16),         acc[4]);
                acc[5] = fmaf(w, __uint_as_float(u.z & 0xffff0000u), acc[5]);
                acc[6] = fmaf(w, __uint_as_float(u.w << 16),         acc[6]);
                acc[7] = fmaf(w, __uint_as_float(u.w & 0xffff0000u), acc[7]);
            }
        }
    }

    // combine the two half-wave partials (same cols in lanes l and l+32)
    #pragma unroll
    for (int i = 0; i < 8; ++i) acc[i] += __shfl_xor(acc[i], 32);

    // reduce softmax denominators across all 64 lanes
    #pragma unroll
    for (int o = 32; o > 0; o >>= 1) {
        s4.x += __shfl_xor(s4.x, o);
        s4.y += __shfl_xor(s4.y, o);
        s4.z += __shfl_xor(s4.z, o);
        s4.w += __shfl_xor(s4.w, o);
    }
    const float rsx = s4.x > 0.f ? 1.f / s4.x : 0.f;
    const float rsy = s4.y > 0.f ? 1.f / s4.y : 0.f;
    const float rsz = s4.z > 0.f ? 1.f / s4.z : 0.f;
    const float rsw = s4.w > 0.f ? 1.f / s4.w : 0.f;
    const float rsh = hh == 0 ? rsx : hh == 1 ? rsy : hh == 2 ? rsz : rsw;
    #pragma unroll
    for (int i = 0; i < 8; ++i) acc[i] *= rsh;

    // head-mean butterfly: lanes {l, l^8, l^16, l^24} hold the 4 heads
    #pragma unroll
    for (int i = 0; i < 8; ++i) {
        acc[i] += __shfl_xor(acc[i], 8);
        acc[i] += __shfl_xor(acc[i], 16);
    }

    const int c0 = 8 * (l & 7);
    const float4 r0 = *(const float4*)(resid + (size_t)d * 64 + c0);
    const float4 r1 = *(const float4*)(resid + (size_t)d * 64 + c0 + 4);
    float v[8];
    v[0] = 0.25f * acc[0] + r0.x;  v[1] = 0.25f * acc[1] + r0.y;
    v[2] = 0.25f * acc[2] + r0.z;  v[3] = 0.25f * acc[3] + r0.w;
    v[4] = 0.25f * acc[4] + r1.x;  v[5] = 0.25f * acc[5] + r1.y;
    v[6] = 0.25f * acc[6] + r1.z;  v[7] = 0.25f * acc[7] + r1.w;

    // LayerNorm stats over the 64 cols (8 families × 8 regs)
    float p = 0.f, p2 = 0.f;
    #pragma unroll
    for (int i = 0; i < 8; ++i) { p += v[i]; p2 += v[i] * v[i]; }
    #pragma unroll
    for (int o = 4; o > 0; o >>= 1) {
        p  += __shfl_xor(p,  o);
        p2 += __shfl_xor(p2, o);
    }
    const float mu  = p * (1.f / 64.f);
    const float var = p2 * (1.f / 64.f) - mu * mu;
    const float inv = 1.f / sqrtf(fmaxf(var, 0.f) + LN_EPS);

    const float4 g0v = *(const float4*)(g + c0);
    const float4 g1v = *(const float4*)(g + c0 + 4);
    const float4 b0v = *(const float4*)(b + c0);
    const float4 b1v = *(const float4*)(b + c0 + 4);
    float y[8];
    y[0] = fmaxf((v[0] - mu) * inv * g0v.x + b0v.x, 0.f);
    y[1] = fmaxf((v[1] - mu) * inv * g0v.y + b0v.y, 0.f);
    y[2] = fmaxf((v[2] - mu) * inv * g0v.z + b0v.z, 0.f);
    y[3] = fmaxf((v[3] - mu) * inv * g0v.w + b0v.w, 0.f);
    y[4] = fmaxf((v[4] - mu) * inv * g1v.x + b1v.x, 0.f);
    y[5] = fmaxf((v[5] - mu) * inv * g1v.y + b1v.y, 0.f);
    y[6] = fmaxf((v[6] - mu) * inv * g1v.z + b1v.z, 0.f);
    y[7] = fmaxf((v[7] - mu) * inv * g1v.w + b1v.w, 0.f);

    if (!FINAL) {
        if (lane < 8) {
            float4 o0 = make_float4(y[0], y[1], y[2], y[3]);
            float4 o1 = make_float4(y[4], y[5], y[6], y[7]);
            *(float4*)(out + (size_t)d * 64 + 8 * lane)     = o0;
            *(float4*)(out + (size_t)d * 64 + 8 * lane + 4) = o1;
        }
    } else {
        if (lane < 8) {
            #pragma unroll
            for (int i = 0; i < 8; ++i) ylds[wv][8 * lane + i] = y[i];
        }
        // wave-internal LDS ordering; then 64-lane matvec: lane = out col
        float o = predb[lane];
        #pragma unroll 4
        for (int k = 0; k < 64; ++k)
            o = fmaf(ylds[wv][k], predw[k * 64 + lane], o);
        out[(size_t)d * 64 + lane] = o;
    }
}

// ---------------------------------------------------------------------------
extern "C" void kernel_launch(void* const* d_in, const int* in_sizes, int n_in,
                              void* d_out, int out_size, void* d_ws, size_t ws_size,
                              hipStream_t stream)
{
    const float* feats = (const float*)d_in[0];
    const int*   src   = (const int*)  d_in[1];
    const int*   dst   = (const int*)  d_in[2];
    const float* W0    = (const float*)d_in[3];
    const float* al0   = (const float*)d_in[4];
    const float* ar0   = (const float*)d_in[5];
    const float* resw0 = (const float*)d_in[6];
    const float* resb0 = (const float*)d_in[7];
    const float* g0    = (const float*)d_in[8];
    const float* b0    = (const float*)d_in[9];
    const float* W1    = (const float*)d_in[10];
    const float* al1   = (const float*)d_in[11];
    const float* ar1   = (const float*)d_in[12];
    const float* resw1 = (const float*)d_in[13];
    const float* resb1 = (const float*)d_in[14];
    const float* g1    = (const float*)d_in[15];
    const float* b1    = (const float*)d_in[16];
    const float* predw = (const float*)d_in[17];
    const float* predb = (const float*)d_in[18];
    float* out = (float*)d_out;

    char* ws = (char*)d_ws;
    int*   rp = (int*)ws;                                   // (N+1) ints
    __hip_bfloat16* fs = (__hip_bfloat16*)(ws + 200192);    // N*256 bf16
    float* el    = (float*)((char*)fs + (size_t)N_NODES * 256 * 2);
    float* er    = el + (size_t)N_NODES * 4;
    float* resid = er + (size_t)N_NODES * 4;
    float* h1    = resid + (size_t)N_NODES * 64;
    short* Vt0   = (short*)(h1 + (size_t)N_NODES * 64);     // 320*128 bf16
    short* Vt1   = Vt0 + 320 * 128;                         // 320*64 bf16

    k_rowptr<<<(N_NODES + 1 + 255) / 256, 256, 0, stream>>>(dst, rp);
    k_wprep<<<(320 * 128 + 320 * 64 + 255) / 256, 256, 0, stream>>>(
        W0, resw0, Vt0, W1, resw1, Vt1);

    k_gemm<128><<<N_NODES / 16, 256, 0, stream>>>(
        feats, Vt0, al0, ar0, resb0, fs, el, er, resid);
    k_agg<false><<<N_NODES / 4, 256, 0, stream>>>(
        rp, src, (const unsigned int*)fs, el, er, resid, g0, b0,
        nullptr, nullptr, h1);

    k_gemm<64><<<N_NODES / 16, 256, 0, stream>>>(
        h1, Vt1, al1, ar1, resb1, fs, el, er, resid);
    k_agg<true><<<N_NODES / 4, 256, 0, stream>>>(
        rp, src, (const unsigned int*)fs, el, er, resid, g1, b1,
        predw, predb, out);
}